// Round 1
// baseline (1601.905 us; speedup 1.0000x reference)
//
#include <hip/hip_runtime.h>
#include <math.h>

#define SEQ   2048
#define NHEAD 16
#define HD    64
#define BSZ   2
#define MTOT  (BSZ*SEQ)   // 4096

// ---------------------------------------------------------------------------
// Generic fp32 GEMM: C[M,N] = A[M,K] @ B[K,N] (+bias) (+SiLU)
// 64x64 tile, 256 threads, 4x4 per thread, K-step 16.
// LDS: As transposed [k][m] stride 65 (conflict-free transpose store),
//      Bs natural   [k][n] stride 68 (float4 aligned, 2-way max).
// ---------------------------------------------------------------------------
template<int ACT>   // 0 = none, 1 = SiLU
__global__ __launch_bounds__(256)
void gemm_kernel(const float* __restrict__ A, const float* __restrict__ B,
                 const float* __restrict__ bias, float* __restrict__ C,
                 int M, int N, int K)
{
    __shared__ float As[16][65];
    __shared__ float Bs[16][68];

    const int t  = threadIdx.x;
    const int tx = t & 15;        // 0..15 -> 4 cols each
    const int ty = t >> 4;        // 0..15 -> 4 rows each
    const int m0 = blockIdx.y * 64;
    const int n0 = blockIdx.x * 64;

    // staging maps
    const int a_row = t >> 2;            // 0..63
    const int a_k   = (t & 3) << 2;      // 0,4,8,12
    const int b_k   = t >> 4;            // 0..15
    const int b_n   = (t & 15) << 2;     // 0..60

    float acc[4][4] = {};

    // prefetch tile 0
    float4 av = *(const float4*)&A[(m0 + a_row) * K + a_k];
    float4 bv = *(const float4*)&B[b_k * N + n0 + b_n];

    for (int k0 = 0; k0 < K; k0 += 16) {
        __syncthreads();
        As[a_k + 0][a_row] = av.x;
        As[a_k + 1][a_row] = av.y;
        As[a_k + 2][a_row] = av.z;
        As[a_k + 3][a_row] = av.w;
        *(float4*)&Bs[b_k][b_n] = bv;
        __syncthreads();

        // prefetch next tile (clamped; last prefetch unused)
        const int kn = (k0 + 16 < K) ? (k0 + 16) : 0;
        av = *(const float4*)&A[(m0 + a_row) * K + kn + a_k];
        bv = *(const float4*)&B[(kn + b_k) * N + n0 + b_n];

        #pragma unroll
        for (int kk = 0; kk < 16; ++kk) {
            float a[4], b[4];
            #pragma unroll
            for (int i = 0; i < 4; ++i) a[i] = As[kk][ty * 4 + i];
            const float4 b4 = *(const float4*)&Bs[kk][tx * 4];
            b[0] = b4.x; b[1] = b4.y; b[2] = b4.z; b[3] = b4.w;
            #pragma unroll
            for (int i = 0; i < 4; ++i)
                #pragma unroll
                for (int j = 0; j < 4; ++j)
                    acc[i][j] += a[i] * b[j];
        }
    }

    #pragma unroll
    for (int i = 0; i < 4; ++i) {
        float r[4];
        #pragma unroll
        for (int j = 0; j < 4; ++j) {
            float x = acc[i][j];
            if (bias) x += bias[n0 + tx * 4 + j];
            if (ACT == 1) x = x / (1.0f + __expf(-x));   // SiLU
            r[j] = x;
        }
        float4 o; o.x = r[0]; o.y = r[1]; o.z = r[2]; o.w = r[3];
        *(float4*)&C[(m0 + ty * 4 + i) * N + n0 + tx * 4] = o;
    }
}

// ---------------------------------------------------------------------------
// Flash attention (fp32). One block = one (b,h) x 64 query rows.
// X = fused qkv [4096, 3072]; mask [2048,2048]; Out [4096, 1024].
// LDS tiles stride-65 (conflict-safe); P reuses the K buffer.
// ---------------------------------------------------------------------------
__global__ __launch_bounds__(256)
void attn_kernel(const float* __restrict__ X, const float* __restrict__ mask,
                 float* __restrict__ Out)
{
    __shared__ float Qt [64][65];   // Qt[d][r]
    __shared__ float KPt[64][65];   // K phase: [d][c]; P phase: [c][r]
    __shared__ float Vs [64][65];   // Vs[c][d]

    const int t   = threadIdx.x;
    const int tx  = t & 15;
    const int ty  = t >> 4;
    const int tx4 = tx * 4;
    const int ty4 = ty * 4;
    const int q0  = blockIdx.x * 64;
    const int bb  = blockIdx.y >> 4;
    const int h   = blockIdx.y & 15;

    const int qbase = (bb * SEQ + q0) * 3072 + h * 64;          // Q block base

    // stage Q transposed
    #pragma unroll
    for (int l = 0; l < 4; ++l) {
        const int flat = l * 1024 + t * 4;
        const int r = flat >> 6, d = flat & 63;
        const float4 v = *(const float4*)&X[qbase + r * 3072 + d];
        Qt[d + 0][r] = v.x; Qt[d + 1][r] = v.y;
        Qt[d + 2][r] = v.z; Qt[d + 3][r] = v.w;
    }

    float o[4][4] = {};
    float m_i[4] = {-1e30f, -1e30f, -1e30f, -1e30f};
    float l_i[4] = {0.f, 0.f, 0.f, 0.f};

    for (int kt = 0; kt < SEQ / 64; ++kt) {
        const int k0 = kt * 64;
        const int kbase = (bb * SEQ + k0) * 3072 + 1024 + h * 64;
        const int vbase = (bb * SEQ + k0) * 3072 + 2048 + h * 64;

        __syncthreads();   // previous iteration done with KPt/Vs
        #pragma unroll
        for (int l = 0; l < 4; ++l) {
            const int flat = l * 1024 + t * 4;
            const int r = flat >> 6, d = flat & 63;
            const float4 kv = *(const float4*)&X[kbase + r * 3072 + d];
            KPt[d + 0][r] = kv.x; KPt[d + 1][r] = kv.y;
            KPt[d + 2][r] = kv.z; KPt[d + 3][r] = kv.w;
            const float4 vv = *(const float4*)&X[vbase + r * 3072 + d];
            Vs[r][d + 0] = vv.x; Vs[r][d + 1] = vv.y;
            Vs[r][d + 2] = vv.z; Vs[r][d + 3] = vv.w;
        }
        __syncthreads();

        // S = Q @ K^T  (4x4 fragment per thread)
        float sc[4][4] = {};
        #pragma unroll 8
        for (int d = 0; d < 64; ++d) {
            float a[4], b[4];
            #pragma unroll
            for (int i = 0; i < 4; ++i) a[i] = Qt[d][ty4 + i];
            #pragma unroll
            for (int j = 0; j < 4; ++j) b[j] = KPt[d][tx4 + j];
            #pragma unroll
            for (int i = 0; i < 4; ++i)
                #pragma unroll
                for (int j = 0; j < 4; ++j)
                    sc[i][j] += a[i] * b[j];
        }

        // scale + mask
        #pragma unroll
        for (int i = 0; i < 4; ++i) {
            const float4 mr = *(const float4*)&mask[(q0 + ty4 + i) * SEQ + k0 + tx4];
            sc[i][0] = sc[i][0] * 0.125f + mr.x;
            sc[i][1] = sc[i][1] * 0.125f + mr.y;
            sc[i][2] = sc[i][2] * 0.125f + mr.z;
            sc[i][3] = sc[i][3] * 0.125f + mr.w;
        }

        // online softmax (row stats across the 16 tx lanes)
        #pragma unroll
        for (int i = 0; i < 4; ++i) {
            float rm = fmaxf(fmaxf(sc[i][0], sc[i][1]), fmaxf(sc[i][2], sc[i][3]));
            rm = fmaxf(rm, __shfl_xor(rm, 1));
            rm = fmaxf(rm, __shfl_xor(rm, 2));
            rm = fmaxf(rm, __shfl_xor(rm, 4));
            rm = fmaxf(rm, __shfl_xor(rm, 8));
            const float mnew  = fmaxf(m_i[i], rm);
            const float alpha = __expf(m_i[i] - mnew);
            float rs = 0.f;
            #pragma unroll
            for (int j = 0; j < 4; ++j) {
                sc[i][j] = __expf(sc[i][j] - mnew);
                rs += sc[i][j];
            }
            rs += __shfl_xor(rs, 1);
            rs += __shfl_xor(rs, 2);
            rs += __shfl_xor(rs, 4);
            rs += __shfl_xor(rs, 8);
            l_i[i] = l_i[i] * alpha + rs;
            m_i[i] = mnew;
            #pragma unroll
            for (int j = 0; j < 4; ++j) o[i][j] *= alpha;
        }

        __syncthreads();   // everyone done reading K from KPt
        // store P transposed: KPt[c][r]
        #pragma unroll
        for (int j = 0; j < 4; ++j)
            #pragma unroll
            for (int i = 0; i < 4; ++i)
                KPt[tx4 + j][ty4 + i] = sc[i][j];
        __syncthreads();

        // O += P @ V
        #pragma unroll 8
        for (int c = 0; c < 64; ++c) {
            float p[4], v[4];
            #pragma unroll
            for (int i = 0; i < 4; ++i) p[i] = KPt[c][ty4 + i];
            #pragma unroll
            for (int j = 0; j < 4; ++j) v[j] = Vs[c][tx4 + j];
            #pragma unroll
            for (int i = 0; i < 4; ++i)
                #pragma unroll
                for (int j = 0; j < 4; ++j)
                    o[i][j] += p[i] * v[j];
        }
    }

    // epilogue: normalize, write [4096, 1024]
    #pragma unroll
    for (int i = 0; i < 4; ++i) {
        const float inv = 1.0f / l_i[i];
        float4 r;
        r.x = o[i][0] * inv; r.y = o[i][1] * inv;
        r.z = o[i][2] * inv; r.w = o[i][3] * inv;
        *(float4*)&Out[(bb * SEQ + q0 + ty4 + i) * (NHEAD * HD) + h * 64 + tx4] = r;
    }
}

// ---------------------------------------------------------------------------
extern "C" void kernel_launch(void* const* d_in, const int* in_sizes, int n_in,
                              void* d_out, int out_size, void* d_ws, size_t ws_size,
                              hipStream_t stream)
{
    const float* seq  = (const float*)d_in[0];   // [2,2048,1024]
    const float* mask = (const float*)d_in[1];   // [2048,2048]
    const float* Wqkv = (const float*)d_in[2];   // [1024,3072]
    const float* W1   = (const float*)d_in[3];   // [1024,2048]
    const float* b1   = (const float*)d_in[4];   // [2048]
    const float* W2   = (const float*)d_in[5];   // [2048,1024]
    const float* b2   = (const float*)d_in[6];   // [1024]
    float* out = (float*)d_out;                  // [4096,1024]

    // workspace layout (64 MiB used):
    //   X   [4096,3072] at 0         (dead after attention)
    //   att [4096,1024] at 12.58M floats
    //   hid [4096,2048] at 0         (overlaps dead X)
    float* X   = (float*)d_ws;
    float* att = X + (size_t)MTOT * 3072;
    float* hid = X;

    // 1) QKV projection
    gemm_kernel<0><<<dim3(3072 / 64, MTOT / 64), 256, 0, stream>>>(
        seq, Wqkv, nullptr, X, MTOT, 3072, 1024);

    // 2) flash attention
    attn_kernel<<<dim3(SEQ / 64, BSZ * NHEAD), 256, 0, stream>>>(X, mask, att);

    // 3) FFN1 + SiLU
    gemm_kernel<1><<<dim3(2048 / 64, MTOT / 64), 256, 0, stream>>>(
        att, W1, b1, hid, MTOT, 2048, 1024);

    // 4) FFN2 + bias
    gemm_kernel<0><<<dim3(1024 / 64, MTOT / 64), 256, 0, stream>>>(
        hid, W2, b2, out, MTOT, 1024, 2048);
}

// Round 2
// 1209.780 us; speedup vs baseline: 1.3241x; 1.3241x over previous
//
#include <hip/hip_runtime.h>
#include <math.h>

#define SEQ   2048
#define NHEAD 16
#define HD    64
#define BSZ   2
#define MTOT  (BSZ*SEQ)   // 4096

typedef __bf16 bf16x8 __attribute__((ext_vector_type(8)));
typedef short  s16x8  __attribute__((ext_vector_type(8)));
typedef short  s16x4  __attribute__((ext_vector_type(4)));
typedef float  f32x4  __attribute__((ext_vector_type(4)));

// round-to-nearest-even fp32 -> bf16 (as raw short)
__device__ __forceinline__ short f2bf(float x) {
    unsigned u = __builtin_bit_cast(unsigned, x);
    u = (u + 0x7fffu + ((u >> 16) & 1u)) >> 16;
    return (short)u;
}
__device__ __forceinline__ float bf2f(short h) {
    unsigned u = ((unsigned)(unsigned short)h) << 16;
    return __builtin_bit_cast(float, u);
}

// ---------------------------------------------------------------------------
// Transpose + split: W[K,N] fp32  ->  Th[N,K], Tl[N,K] bf16 (hi/lo residual)
// 32x32 tile, 256 threads.
// ---------------------------------------------------------------------------
__global__ __launch_bounds__(256)
void tsplit_kernel(const float* __restrict__ W, short* __restrict__ Th,
                   short* __restrict__ Tl, int K, int N)
{
    __shared__ float T[32][33];
    const int t  = threadIdx.x;
    const int k0 = blockIdx.x * 32;
    const int n0 = blockIdx.y * 32;
    {
        const int kl = t >> 3;          // 0..31
        const int nl = (t & 7) * 4;     // 0..28
        const float4 v = *(const float4*)&W[(size_t)(k0 + kl) * N + n0 + nl];
        T[nl + 0][kl] = v.x; T[nl + 1][kl] = v.y;
        T[nl + 2][kl] = v.z; T[nl + 3][kl] = v.w;
    }
    __syncthreads();
    {
        const int nl = t >> 3;
        const int kl = (t & 7) * 4;
        s16x4 h, l;
        #pragma unroll
        for (int c = 0; c < 4; ++c) {
            const float x = T[nl][kl + c];
            const short hb = f2bf(x);
            h[c] = hb;
            l[c] = f2bf(x - bf2f(hb));
        }
        const size_t o = (size_t)(n0 + nl) * K + k0 + kl;
        *(s16x4*)&Th[o] = h;
        *(s16x4*)&Tl[o] = l;
    }
}

// ---------------------------------------------------------------------------
// bf16x3 split MFMA GEMM: C[M,N] = A[M,K](fp32) @ B (+bias)(+SiLU)
// B supplied pre-transposed+split: Bhi/Blo [N,K] bf16.
// Block 128x128, 256 threads = 4 waves, wave tile 64x64 = 4x4 frags of
// mfma_f32_16x16x32_bf16. BK=32. LDS row stride 40 shorts (80 B) so the
// fragment ds_read_b128 pattern is bank-balanced.
// acc += Ahi*Bhi + Ahi*Blo + Alo*Bhi   (Alo*Blo dropped, ~2^-18 rel)
// ---------------------------------------------------------------------------
#define BM  128
#define BN  128
#define BK  32
#define LDA 40

template<int ACT>   // 0 = none, 1 = SiLU
__global__ __launch_bounds__(256, 2)
void gemm_bf16x3(const float* __restrict__ A,
                 const short* __restrict__ Bhi, const short* __restrict__ Blo,
                 const float* __restrict__ bias, float* __restrict__ C,
                 int M, int N, int K)
{
    __shared__ short Ah[BM * LDA];
    __shared__ short Al[BM * LDA];
    __shared__ short Bh[BN * LDA];
    __shared__ short Bl[BN * LDA];

    const int t    = threadIdx.x;
    const int m0   = blockIdx.y * BM;
    const int n0   = blockIdx.x * BN;
    const int wave = t >> 6;
    const int lane = t & 63;
    const int r    = lane & 15;
    const int q    = lane >> 4;
    const int wm   = (wave & 1) * 64;
    const int wn   = (wave >> 1) * 64;

    // staging maps
    const int a_row = t >> 3;      // 0..31 (+s*32)
    const int a_g   = t & 7;       // float4 group within 32-k chunk
    const int b_row = t >> 2;      // 0..63 (+s*64)
    const int b_g   = t & 3;       // 8-short group

    f32x4 zero = {0.f, 0.f, 0.f, 0.f};
    f32x4 acc[4][4];
    #pragma unroll
    for (int i = 0; i < 4; ++i)
        #pragma unroll
        for (int j = 0; j < 4; ++j) acc[i][j] = zero;

    float4 areg[4];
    uint4  bhreg[2], blreg[2];

    // prefetch k-chunk 0
    #pragma unroll
    for (int s = 0; s < 4; ++s)
        areg[s] = *(const float4*)&A[(size_t)(m0 + a_row + s * 32) * K + a_g * 4];
    #pragma unroll
    for (int s = 0; s < 2; ++s) {
        const size_t o = (size_t)(n0 + b_row + s * 64) * K + b_g * 8;
        bhreg[s] = *(const uint4*)&Bhi[o];
        blreg[s] = *(const uint4*)&Blo[o];
    }

    for (int k0 = 0; k0 < K; k0 += BK) {
        __syncthreads();
        // stage A (convert fp32 -> hi/lo bf16)
        #pragma unroll
        for (int s = 0; s < 4; ++s) {
            const float4 v = areg[s];
            const float xs[4] = {v.x, v.y, v.z, v.w};
            s16x4 h, l;
            #pragma unroll
            for (int c = 0; c < 4; ++c) {
                const short hb = f2bf(xs[c]);
                h[c] = hb;
                l[c] = f2bf(xs[c] - bf2f(hb));
            }
            const int off = (a_row + s * 32) * LDA + a_g * 4;
            *(s16x4*)&Ah[off] = h;
            *(s16x4*)&Al[off] = l;
        }
        // stage B (already bf16 hi/lo)
        #pragma unroll
        for (int s = 0; s < 2; ++s) {
            const int off = (b_row + s * 64) * LDA + b_g * 8;
            *(uint4*)&Bh[off] = bhreg[s];
            *(uint4*)&Bl[off] = blreg[s];
        }
        __syncthreads();

        // prefetch next k-chunk (clamped; stays in flight over the MFMAs)
        const int kn = (k0 + BK < K) ? (k0 + BK) : 0;
        #pragma unroll
        for (int s = 0; s < 4; ++s)
            areg[s] = *(const float4*)&A[(size_t)(m0 + a_row + s * 32) * K + kn + a_g * 4];
        #pragma unroll
        for (int s = 0; s < 2; ++s) {
            const size_t o = (size_t)(n0 + b_row + s * 64) * K + kn + b_g * 8;
            bhreg[s] = *(const uint4*)&Bhi[o];
            blreg[s] = *(const uint4*)&Blo[o];
        }

        // fragment loads (ds_read_b128, 16B aligned: row*80 + q*16)
        bf16x8 afh[4], afl[4], bfh[4], bfl[4];
        #pragma unroll
        for (int i = 0; i < 4; ++i) {
            const int row = wm + i * 16 + r;
            afh[i] = __builtin_bit_cast(bf16x8, *(const s16x8*)&Ah[row * LDA + q * 8]);
            afl[i] = __builtin_bit_cast(bf16x8, *(const s16x8*)&Al[row * LDA + q * 8]);
        }
        #pragma unroll
        for (int j = 0; j < 4; ++j) {
            const int row = wn + j * 16 + r;
            bfh[j] = __builtin_bit_cast(bf16x8, *(const s16x8*)&Bh[row * LDA + q * 8]);
            bfl[j] = __builtin_bit_cast(bf16x8, *(const s16x8*)&Bl[row * LDA + q * 8]);
        }

        #pragma unroll
        for (int i = 0; i < 4; ++i)
            #pragma unroll
            for (int j = 0; j < 4; ++j) {
                acc[i][j] = __builtin_amdgcn_mfma_f32_16x16x32_bf16(afh[i], bfh[j], acc[i][j], 0, 0, 0);
                acc[i][j] = __builtin_amdgcn_mfma_f32_16x16x32_bf16(afh[i], bfl[j], acc[i][j], 0, 0, 0);
                acc[i][j] = __builtin_amdgcn_mfma_f32_16x16x32_bf16(afl[i], bfh[j], acc[i][j], 0, 0, 0);
            }
    }

    // epilogue: C/D layout col=lane&15, row=quad*4+reg
    #pragma unroll
    for (int i = 0; i < 4; ++i)
        #pragma unroll
        for (int j = 0; j < 4; ++j) {
            const int col = n0 + wn + j * 16 + r;
            const float bv = bias ? bias[col] : 0.f;
            #pragma unroll
            for (int g = 0; g < 4; ++g) {
                const int row = m0 + wm + i * 16 + q * 4 + g;
                float x = acc[i][j][g] + bv;
                if (ACT == 1) x = x / (1.0f + __expf(-x));
                C[(size_t)row * N + col] = x;
            }
        }
}

// ---------------------------------------------------------------------------
// Flash attention (fp32) — unchanged from round 0 (known-good).
// ---------------------------------------------------------------------------
__global__ __launch_bounds__(256)
void attn_kernel(const float* __restrict__ X, const float* __restrict__ mask,
                 float* __restrict__ Out)
{
    __shared__ float Qt [64][65];
    __shared__ float KPt[64][65];
    __shared__ float Vs [64][65];

    const int t   = threadIdx.x;
    const int tx  = t & 15;
    const int ty  = t >> 4;
    const int tx4 = tx * 4;
    const int ty4 = ty * 4;
    const int q0  = blockIdx.x * 64;
    const int bb  = blockIdx.y >> 4;
    const int h   = blockIdx.y & 15;

    const int qbase = (bb * SEQ + q0) * 3072 + h * 64;

    #pragma unroll
    for (int l = 0; l < 4; ++l) {
        const int flat = l * 1024 + t * 4;
        const int rr = flat >> 6, d = flat & 63;
        const float4 v = *(const float4*)&X[qbase + rr * 3072 + d];
        Qt[d + 0][rr] = v.x; Qt[d + 1][rr] = v.y;
        Qt[d + 2][rr] = v.z; Qt[d + 3][rr] = v.w;
    }

    float o[4][4] = {};
    float m_i[4] = {-1e30f, -1e30f, -1e30f, -1e30f};
    float l_i[4] = {0.f, 0.f, 0.f, 0.f};

    for (int kt = 0; kt < SEQ / 64; ++kt) {
        const int k0 = kt * 64;
        const int kbase = (bb * SEQ + k0) * 3072 + 1024 + h * 64;
        const int vbase = (bb * SEQ + k0) * 3072 + 2048 + h * 64;

        __syncthreads();
        #pragma unroll
        for (int l = 0; l < 4; ++l) {
            const int flat = l * 1024 + t * 4;
            const int rr = flat >> 6, d = flat & 63;
            const float4 kv = *(const float4*)&X[kbase + rr * 3072 + d];
            KPt[d + 0][rr] = kv.x; KPt[d + 1][rr] = kv.y;
            KPt[d + 2][rr] = kv.z; KPt[d + 3][rr] = kv.w;
            const float4 vv = *(const float4*)&X[vbase + rr * 3072 + d];
            Vs[rr][d + 0] = vv.x; Vs[rr][d + 1] = vv.y;
            Vs[rr][d + 2] = vv.z; Vs[rr][d + 3] = vv.w;
        }
        __syncthreads();

        float sc[4][4] = {};
        #pragma unroll 8
        for (int d = 0; d < 64; ++d) {
            float a[4], b[4];
            #pragma unroll
            for (int i = 0; i < 4; ++i) a[i] = Qt[d][ty4 + i];
            #pragma unroll
            for (int j = 0; j < 4; ++j) b[j] = KPt[d][tx4 + j];
            #pragma unroll
            for (int i = 0; i < 4; ++i)
                #pragma unroll
                for (int j = 0; j < 4; ++j)
                    sc[i][j] += a[i] * b[j];
        }

        #pragma unroll
        for (int i = 0; i < 4; ++i) {
            const float4 mr = *(const float4*)&mask[(q0 + ty4 + i) * SEQ + k0 + tx4];
            sc[i][0] = sc[i][0] * 0.125f + mr.x;
            sc[i][1] = sc[i][1] * 0.125f + mr.y;
            sc[i][2] = sc[i][2] * 0.125f + mr.z;
            sc[i][3] = sc[i][3] * 0.125f + mr.w;
        }

        #pragma unroll
        for (int i = 0; i < 4; ++i) {
            float rm = fmaxf(fmaxf(sc[i][0], sc[i][1]), fmaxf(sc[i][2], sc[i][3]));
            rm = fmaxf(rm, __shfl_xor(rm, 1));
            rm = fmaxf(rm, __shfl_xor(rm, 2));
            rm = fmaxf(rm, __shfl_xor(rm, 4));
            rm = fmaxf(rm, __shfl_xor(rm, 8));
            const float mnew  = fmaxf(m_i[i], rm);
            const float alpha = __expf(m_i[i] - mnew);
            float rs = 0.f;
            #pragma unroll
            for (int j = 0; j < 4; ++j) {
                sc[i][j] = __expf(sc[i][j] - mnew);
                rs += sc[i][j];
            }
            rs += __shfl_xor(rs, 1);
            rs += __shfl_xor(rs, 2);
            rs += __shfl_xor(rs, 4);
            rs += __shfl_xor(rs, 8);
            l_i[i] = l_i[i] * alpha + rs;
            m_i[i] = mnew;
            #pragma unroll
            for (int j = 0; j < 4; ++j) o[i][j] *= alpha;
        }

        __syncthreads();
        #pragma unroll
        for (int j = 0; j < 4; ++j)
            #pragma unroll
            for (int i = 0; i < 4; ++i)
                KPt[tx4 + j][ty4 + i] = sc[i][j];
        __syncthreads();

        #pragma unroll 8
        for (int c = 0; c < 64; ++c) {
            float p[4], v[4];
            #pragma unroll
            for (int i = 0; i < 4; ++i) p[i] = KPt[c][ty4 + i];
            #pragma unroll
            for (int j = 0; j < 4; ++j) v[j] = Vs[c][tx4 + j];
            #pragma unroll
            for (int i = 0; i < 4; ++i)
                #pragma unroll
                for (int j = 0; j < 4; ++j)
                    o[i][j] += p[i] * v[j];
        }
    }

    #pragma unroll
    for (int i = 0; i < 4; ++i) {
        const float inv = 1.0f / l_i[i];
        float4 rr;
        rr.x = o[i][0] * inv; rr.y = o[i][1] * inv;
        rr.z = o[i][2] * inv; rr.w = o[i][3] * inv;
        *(float4*)&Out[(bb * SEQ + q0 + ty4 + i) * (NHEAD * HD) + h * 64 + tx4] = rr;
    }
}

// ---------------------------------------------------------------------------
extern "C" void kernel_launch(void* const* d_in, const int* in_sizes, int n_in,
                              void* d_out, int out_size, void* d_ws, size_t ws_size,
                              hipStream_t stream)
{
    const float* seq  = (const float*)d_in[0];   // [2,2048,1024]
    const float* mask = (const float*)d_in[1];   // [2048,2048]
    const float* Wqkv = (const float*)d_in[2];   // [1024,3072]
    const float* W1   = (const float*)d_in[3];   // [1024,2048]
    const float* b1   = (const float*)d_in[4];   // [2048]
    const float* W2   = (const float*)d_in[5];   // [2048,1024]
    const float* b2   = (const float*)d_in[6];   // [1024]
    float* out = (float*)d_out;                  // [4096,1024]

    // workspace timeline (peak 64 MiB, same as round-0):
    //   [0, 50.33M)      : Xf fp32 (QKV out / attn in)   -> later hid fp32 (33.55M)
    //   [50.33M, 67.11M) : WtQ hi/lo (12.58M, dead after gemm1) -> att fp32 (16.78M)
    //   [33.55M, 41.94M) : Wt1 hi/lo (after attn, Xf dead)
    //   [41.94M, 50.33M) : Wt2 hi/lo (after attn)
    char* base = (char*)d_ws;
    float* Xf   = (float*)base;
    float* hid  = (float*)base;
    float* att  = (float*)(base + 50331648);
    short* WtQh = (short*)(base + 50331648);
    short* WtQl = WtQh + (size_t)3072 * 1024;
    short* Wt1h = (short*)(base + 33554432);
    short* Wt1l = Wt1h + (size_t)2048 * 1024;
    short* Wt2h = (short*)(base + 41943040);
    short* Wt2l = Wt2h + (size_t)2048 * 1024;

    // 1) transpose+split Wqkv -> [3072,1024] hi/lo
    tsplit_kernel<<<dim3(1024 / 32, 3072 / 32), 256, 0, stream>>>(Wqkv, WtQh, WtQl, 1024, 3072);

    // 2) QKV projection (MFMA)
    gemm_bf16x3<0><<<dim3(3072 / 128, MTOT / 128), 256, 0, stream>>>(
        seq, WtQh, WtQl, nullptr, Xf, MTOT, 3072, 1024);

    // 3) flash attention (fp32, unchanged) -> att (overwrites WtQ region)
    attn_kernel<<<dim3(SEQ / 64, BSZ * NHEAD), 256, 0, stream>>>(Xf, mask, att);

    // 4) transpose+split W1, W2 (Xf region now dead)
    tsplit_kernel<<<dim3(1024 / 32, 2048 / 32), 256, 0, stream>>>(W1, Wt1h, Wt1l, 1024, 2048);
    tsplit_kernel<<<dim3(2048 / 32, 1024 / 32), 256, 0, stream>>>(W2, Wt2h, Wt2l, 2048, 1024);

    // 5) FFN1 + SiLU (MFMA) -> hid fp32 @0
    gemm_bf16x3<1><<<dim3(2048 / 128, MTOT / 128), 256, 0, stream>>>(
        att, Wt1h, Wt1l, b1, hid, MTOT, 2048, 1024);

    // 6) FFN2 + bias (MFMA) -> out
    gemm_bf16x3<0><<<dim3(1024 / 128, MTOT / 128), 256, 0, stream>>>(
        hid, Wt2h, Wt2l, b2, out, MTOT, 1024, 2048);
}

// Round 3
// 719.555 us; speedup vs baseline: 2.2262x; 1.6813x over previous
//
#include <hip/hip_runtime.h>
#include <math.h>

#define SEQ   2048
#define NHEAD 16
#define HD    64
#define BSZ   2
#define MTOT  (BSZ*SEQ)   // 4096

typedef __bf16 bf16x8 __attribute__((ext_vector_type(8)));
typedef short  s16x8  __attribute__((ext_vector_type(8)));
typedef short  s16x4  __attribute__((ext_vector_type(4)));
typedef float  f32x4  __attribute__((ext_vector_type(4)));

// round-to-nearest-even fp32 -> bf16 (as raw short)
__device__ __forceinline__ short f2bf(float x) {
    unsigned u = __builtin_bit_cast(unsigned, x);
    u = (u + 0x7fffu + ((u >> 16) & 1u)) >> 16;
    return (short)u;
}
__device__ __forceinline__ float bf2f(short h) {
    unsigned u = ((unsigned)(unsigned short)h) << 16;
    return __builtin_bit_cast(float, u);
}

// ---------------------------------------------------------------------------
// Transpose + split: W[K,N] fp32 -> Th[N,K], Tl[N,K] bf16 (hi/lo residual)
// ---------------------------------------------------------------------------
__global__ __launch_bounds__(256)
void tsplit_kernel(const float* __restrict__ W, short* __restrict__ Th,
                   short* __restrict__ Tl, int K, int N)
{
    __shared__ float T[32][33];
    const int t  = threadIdx.x;
    const int k0 = blockIdx.x * 32;
    const int n0 = blockIdx.y * 32;
    {
        const int kl = t >> 3;
        const int nl = (t & 7) * 4;
        const float4 v = *(const float4*)&W[(size_t)(k0 + kl) * N + n0 + nl];
        T[nl + 0][kl] = v.x; T[nl + 1][kl] = v.y;
        T[nl + 2][kl] = v.z; T[nl + 3][kl] = v.w;
    }
    __syncthreads();
    {
        const int nl = t >> 3;
        const int kl = (t & 7) * 4;
        s16x4 h, l;
        #pragma unroll
        for (int c = 0; c < 4; ++c) {
            const float x = T[nl][kl + c];
            const short hb = f2bf(x);
            h[c] = hb;
            l[c] = f2bf(x - bf2f(hb));
        }
        const size_t o = (size_t)(n0 + nl) * K + k0 + kl;
        *(s16x4*)&Th[o] = h;
        *(s16x4*)&Tl[o] = l;
    }
}

// ---------------------------------------------------------------------------
// bf16x3 split MFMA GEMM (unchanged from round 1 — known good)
// ---------------------------------------------------------------------------
#define BM  128
#define BN  128
#define BK  32
#define LDA 40

template<int ACT>
__global__ __launch_bounds__(256, 2)
void gemm_bf16x3(const float* __restrict__ A,
                 const short* __restrict__ Bhi, const short* __restrict__ Blo,
                 const float* __restrict__ bias, float* __restrict__ C,
                 int M, int N, int K)
{
    __shared__ short Ah[BM * LDA];
    __shared__ short Al[BM * LDA];
    __shared__ short Bh[BN * LDA];
    __shared__ short Bl[BN * LDA];

    const int t    = threadIdx.x;
    const int m0   = blockIdx.y * BM;
    const int n0   = blockIdx.x * BN;
    const int wave = t >> 6;
    const int lane = t & 63;
    const int r    = lane & 15;
    const int q    = lane >> 4;
    const int wm   = (wave & 1) * 64;
    const int wn   = (wave >> 1) * 64;

    const int a_row = t >> 3;
    const int a_g   = t & 7;
    const int b_row = t >> 2;
    const int b_g   = t & 3;

    f32x4 zero = {0.f, 0.f, 0.f, 0.f};
    f32x4 acc[4][4];
    #pragma unroll
    for (int i = 0; i < 4; ++i)
        #pragma unroll
        for (int j = 0; j < 4; ++j) acc[i][j] = zero;

    float4 areg[4];
    uint4  bhreg[2], blreg[2];

    #pragma unroll
    for (int s = 0; s < 4; ++s)
        areg[s] = *(const float4*)&A[(size_t)(m0 + a_row + s * 32) * K + a_g * 4];
    #pragma unroll
    for (int s = 0; s < 2; ++s) {
        const size_t o = (size_t)(n0 + b_row + s * 64) * K + b_g * 8;
        bhreg[s] = *(const uint4*)&Bhi[o];
        blreg[s] = *(const uint4*)&Blo[o];
    }

    for (int k0 = 0; k0 < K; k0 += BK) {
        __syncthreads();
        #pragma unroll
        for (int s = 0; s < 4; ++s) {
            const float4 v = areg[s];
            const float xs[4] = {v.x, v.y, v.z, v.w};
            s16x4 h, l;
            #pragma unroll
            for (int c = 0; c < 4; ++c) {
                const short hb = f2bf(xs[c]);
                h[c] = hb;
                l[c] = f2bf(xs[c] - bf2f(hb));
            }
            const int off = (a_row + s * 32) * LDA + a_g * 4;
            *(s16x4*)&Ah[off] = h;
            *(s16x4*)&Al[off] = l;
        }
        #pragma unroll
        for (int s = 0; s < 2; ++s) {
            const int off = (b_row + s * 64) * LDA + b_g * 8;
            *(uint4*)&Bh[off] = bhreg[s];
            *(uint4*)&Bl[off] = blreg[s];
        }
        __syncthreads();

        const int kn = (k0 + BK < K) ? (k0 + BK) : 0;
        #pragma unroll
        for (int s = 0; s < 4; ++s)
            areg[s] = *(const float4*)&A[(size_t)(m0 + a_row + s * 32) * K + kn + a_g * 4];
        #pragma unroll
        for (int s = 0; s < 2; ++s) {
            const size_t o = (size_t)(n0 + b_row + s * 64) * K + kn + b_g * 8;
            bhreg[s] = *(const uint4*)&Bhi[o];
            blreg[s] = *(const uint4*)&Blo[o];
        }

        bf16x8 afh[4], afl[4], bfh[4], bfl[4];
        #pragma unroll
        for (int i = 0; i < 4; ++i) {
            const int row = wm + i * 16 + r;
            afh[i] = __builtin_bit_cast(bf16x8, *(const s16x8*)&Ah[row * LDA + q * 8]);
            afl[i] = __builtin_bit_cast(bf16x8, *(const s16x8*)&Al[row * LDA + q * 8]);
        }
        #pragma unroll
        for (int j = 0; j < 4; ++j) {
            const int row = wn + j * 16 + r;
            bfh[j] = __builtin_bit_cast(bf16x8, *(const s16x8*)&Bh[row * LDA + q * 8]);
            bfl[j] = __builtin_bit_cast(bf16x8, *(const s16x8*)&Bl[row * LDA + q * 8]);
        }

        #pragma unroll
        for (int i = 0; i < 4; ++i)
            #pragma unroll
            for (int j = 0; j < 4; ++j) {
                acc[i][j] = __builtin_amdgcn_mfma_f32_16x16x32_bf16(afh[i], bfh[j], acc[i][j], 0, 0, 0);
                acc[i][j] = __builtin_amdgcn_mfma_f32_16x16x32_bf16(afh[i], bfl[j], acc[i][j], 0, 0, 0);
                acc[i][j] = __builtin_amdgcn_mfma_f32_16x16x32_bf16(afl[i], bfh[j], acc[i][j], 0, 0, 0);
            }
    }

    #pragma unroll
    for (int i = 0; i < 4; ++i)
        #pragma unroll
        for (int j = 0; j < 4; ++j) {
            const int col = n0 + wn + j * 16 + r;
            const float bv = bias ? bias[col] : 0.f;
            #pragma unroll
            for (int g = 0; g < 4; ++g) {
                const int row = m0 + wm + i * 16 + q * 4 + g;
                float x = acc[i][j][g] + bv;
                if (ACT == 1) x = x / (1.0f + __expf(-x));
                C[(size_t)row * N + col] = x;
            }
        }
}

// ---------------------------------------------------------------------------
// MFMA flash attention, bf16x3 split everywhere.
// Block: 128 q-rows x one (b,h). 4 waves x 32 q-rows. K-tile = 64 keys.
// Q frags: global->reg once (scale 1/8 folded in). K: LDS [c][d] hi/lo,
// B-operand of S=Q@K^T. V: LDS transposed [d][c] hi/lo, B-operand of O=P@V.
// P: C-layout regs -> LDS (reusing K buffer) -> A-layout frags, hi/lo split.
// Online softmax in registers via quad-local shfl_xor.
// ---------------------------------------------------------------------------
#define ALD 72   // shorts per LDS row (64 + 8 pad; 144 B, 16B-aligned)

__global__ __launch_bounds__(256, 2)
void attn_mfma(const float* __restrict__ X, const float* __restrict__ mask,
               float* __restrict__ Out)
{
    __shared__ short KPh[128 * ALD];   // K (rows 0..63) then P (rows 0..127)
    __shared__ short KPl[128 * ALD];
    __shared__ short Vth[64 * ALD];    // V transposed [d][c]
    __shared__ short Vtl[64 * ALD];

    const int t    = threadIdx.x;
    const int lane = t & 63;
    const int w    = t >> 6;
    const int r    = lane & 15;
    const int qd   = lane >> 4;
    const int b    = blockIdx.x >> 4;
    const int h    = blockIdx.x & 15;
    const int q0   = blockIdx.y * 128;

    // ---- Q fragments: global -> registers, 0.125 scale folded in ----
    bf16x8 qh[2][2], ql[2][2];
    #pragma unroll
    for (int i = 0; i < 2; ++i) {
        const size_t qoff = (size_t)(b * SEQ + q0 + w * 32 + i * 16 + r) * 3072 + h * 64;
        #pragma unroll
        for (int ks = 0; ks < 2; ++ks) {
            const float4 v0 = *(const float4*)&X[qoff + ks * 32 + qd * 8];
            const float4 v1 = *(const float4*)&X[qoff + ks * 32 + qd * 8 + 4];
            const float xs[8] = {v0.x, v0.y, v0.z, v0.w, v1.x, v1.y, v1.z, v1.w};
            s16x8 hh, ll;
            #pragma unroll
            for (int c = 0; c < 8; ++c) {
                const float x = xs[c] * 0.125f;
                const short hb = f2bf(x);
                hh[c] = hb;
                ll[c] = f2bf(x - bf2f(hb));
            }
            qh[i][ks] = __builtin_bit_cast(bf16x8, hh);
            ql[i][ks] = __builtin_bit_cast(bf16x8, ll);
        }
    }

    // staging maps
    const int kc = t >> 2;              // key row 0..63
    const int kg = (t & 3) * 16;        // col group
    const int vc = t & 63;              // key col (for V transpose)
    const int vg = (t >> 6) * 16;       // d group

    f32x4 O[2][4];
    #pragma unroll
    for (int i = 0; i < 2; ++i)
        #pragma unroll
        for (int j = 0; j < 4; ++j) O[i][j] = (f32x4){0.f, 0.f, 0.f, 0.f};
    float m_i[2][4], l_i[2][4];
    #pragma unroll
    for (int i = 0; i < 2; ++i)
        #pragma unroll
        for (int g = 0; g < 4; ++g) { m_i[i][g] = -1e30f; l_i[i][g] = 0.f; }

    for (int kt = 0; kt < SEQ / 64; ++kt) {
        const int k0 = kt * 64;
        const size_t kbase = (size_t)(b * SEQ + k0) * 3072 + 1024 + h * 64;
        const size_t vbase = (size_t)(b * SEQ + k0) * 3072 + 2048 + h * 64;

        __syncthreads();   // prior tile's P/V reads done
        // stage K [c][d] hi/lo
        #pragma unroll
        for (int s = 0; s < 4; ++s) {
            const int col = kg + s * 4;
            const float4 kv = *(const float4*)&X[kbase + (size_t)kc * 3072 + col];
            const float xs[4] = {kv.x, kv.y, kv.z, kv.w};
            s16x4 hh, ll;
            #pragma unroll
            for (int c = 0; c < 4; ++c) {
                const short hb = f2bf(xs[c]);
                hh[c] = hb;
                ll[c] = f2bf(xs[c] - bf2f(hb));
            }
            *(s16x4*)&KPh[kc * ALD + col] = hh;
            *(s16x4*)&KPl[kc * ALD + col] = ll;
        }
        // stage V transposed [d][c] hi/lo
        #pragma unroll
        for (int s = 0; s < 4; ++s) {
            const int d0 = vg + s * 4;
            const float4 vv = *(const float4*)&X[vbase + (size_t)vc * 3072 + d0];
            const float xs[4] = {vv.x, vv.y, vv.z, vv.w};
            #pragma unroll
            for (int c = 0; c < 4; ++c) {
                const short hb = f2bf(xs[c]);
                Vth[(d0 + c) * ALD + vc] = hb;
                Vtl[(d0 + c) * ALD + vc] = f2bf(xs[c] - bf2f(hb));
            }
        }
        __syncthreads();

        // mask prefetch (overlaps with MFMAs below)
        float mreg[2][4][4];
        #pragma unroll
        for (int i = 0; i < 2; ++i)
            #pragma unroll
            for (int g = 0; g < 4; ++g) {
                const size_t mrow = (size_t)(q0 + w * 32 + i * 16 + qd * 4 + g) * SEQ + k0;
                #pragma unroll
                for (int j = 0; j < 4; ++j)
                    mreg[i][g][j] = mask[mrow + j * 16 + r];
            }

        // S = Q @ K^T
        f32x4 S[2][4];
        #pragma unroll
        for (int i = 0; i < 2; ++i)
            #pragma unroll
            for (int j = 0; j < 4; ++j) S[i][j] = (f32x4){0.f, 0.f, 0.f, 0.f};
        #pragma unroll
        for (int ks = 0; ks < 2; ++ks) {
            bf16x8 kfh[4], kfl[4];
            #pragma unroll
            for (int j = 0; j < 4; ++j) {
                kfh[j] = __builtin_bit_cast(bf16x8, *(const s16x8*)&KPh[(j * 16 + r) * ALD + ks * 32 + qd * 8]);
                kfl[j] = __builtin_bit_cast(bf16x8, *(const s16x8*)&KPl[(j * 16 + r) * ALD + ks * 32 + qd * 8]);
            }
            #pragma unroll
            for (int i = 0; i < 2; ++i)
                #pragma unroll
                for (int j = 0; j < 4; ++j) {
                    S[i][j] = __builtin_amdgcn_mfma_f32_16x16x32_bf16(qh[i][ks], kfh[j], S[i][j], 0, 0, 0);
                    S[i][j] = __builtin_amdgcn_mfma_f32_16x16x32_bf16(qh[i][ks], kfl[j], S[i][j], 0, 0, 0);
                    S[i][j] = __builtin_amdgcn_mfma_f32_16x16x32_bf16(ql[i][ks], kfh[j], S[i][j], 0, 0, 0);
                }
        }

        // mask + online softmax (all in registers; row stats via quad shfl)
        #pragma unroll
        for (int i = 0; i < 2; ++i)
            #pragma unroll
            for (int g = 0; g < 4; ++g) {
                float sv[4];
                #pragma unroll
                for (int j = 0; j < 4; ++j) sv[j] = S[i][j][g] + mreg[i][g][j];
                float mx = fmaxf(fmaxf(sv[0], sv[1]), fmaxf(sv[2], sv[3]));
                mx = fmaxf(mx, __shfl_xor(mx, 1));
                mx = fmaxf(mx, __shfl_xor(mx, 2));
                mx = fmaxf(mx, __shfl_xor(mx, 4));
                mx = fmaxf(mx, __shfl_xor(mx, 8));
                const float mnew  = fmaxf(m_i[i][g], mx);
                const float alpha = __expf(m_i[i][g] - mnew);
                float rs = 0.f;
                #pragma unroll
                for (int j = 0; j < 4; ++j) {
                    const float p = __expf(sv[j] - mnew);
                    S[i][j][g] = p;        // stash P
                    rs += p;
                }
                rs += __shfl_xor(rs, 1);
                rs += __shfl_xor(rs, 2);
                rs += __shfl_xor(rs, 4);
                rs += __shfl_xor(rs, 8);
                l_i[i][g] = l_i[i][g] * alpha + rs;
                m_i[i][g] = mnew;
                #pragma unroll
                for (int j = 0; j < 4; ++j) O[i][j][g] *= alpha;
            }

        __syncthreads();   // everyone done reading K
        // write P (hi/lo) into the K buffer, [qrow][key] layout
        #pragma unroll
        for (int i = 0; i < 2; ++i)
            #pragma unroll
            for (int j = 0; j < 4; ++j)
                #pragma unroll
                for (int g = 0; g < 4; ++g) {
                    const int prow = w * 32 + i * 16 + qd * 4 + g;
                    const float p  = S[i][j][g];
                    const short ph = f2bf(p);
                    KPh[prow * ALD + j * 16 + r] = ph;
                    KPl[prow * ALD + j * 16 + r] = f2bf(p - bf2f(ph));
                }
        __syncthreads();

        // O += P @ V
        #pragma unroll
        for (int ks = 0; ks < 2; ++ks) {
            bf16x8 pfh[2], pfl[2], vfh[4], vfl[4];
            #pragma unroll
            for (int i = 0; i < 2; ++i) {
                pfh[i] = __builtin_bit_cast(bf16x8, *(const s16x8*)&KPh[(w * 32 + i * 16 + r) * ALD + ks * 32 + qd * 8]);
                pfl[i] = __builtin_bit_cast(bf16x8, *(const s16x8*)&KPl[(w * 32 + i * 16 + r) * ALD + ks * 32 + qd * 8]);
            }
            #pragma unroll
            for (int j = 0; j < 4; ++j) {
                vfh[j] = __builtin_bit_cast(bf16x8, *(const s16x8*)&Vth[(j * 16 + r) * ALD + ks * 32 + qd * 8]);
                vfl[j] = __builtin_bit_cast(bf16x8, *(const s16x8*)&Vtl[(j * 16 + r) * ALD + ks * 32 + qd * 8]);
            }
            #pragma unroll
            for (int i = 0; i < 2; ++i)
                #pragma unroll
                for (int j = 0; j < 4; ++j) {
                    O[i][j] = __builtin_amdgcn_mfma_f32_16x16x32_bf16(pfh[i], vfh[j], O[i][j], 0, 0, 0);
                    O[i][j] = __builtin_amdgcn_mfma_f32_16x16x32_bf16(pfh[i], vfl[j], O[i][j], 0, 0, 0);
                    O[i][j] = __builtin_amdgcn_mfma_f32_16x16x32_bf16(pfl[i], vfh[j], O[i][j], 0, 0, 0);
                }
        }
    }

    // epilogue: normalize + store
    #pragma unroll
    for (int i = 0; i < 2; ++i)
        #pragma unroll
        for (int g = 0; g < 4; ++g) {
            const float inv = 1.0f / l_i[i][g];
            const int row = q0 + w * 32 + i * 16 + qd * 4 + g;
            #pragma unroll
            for (int j = 0; j < 4; ++j)
                Out[(size_t)(b * SEQ + row) * 1024 + h * 64 + j * 16 + r] = O[i][j][g] * inv;
        }
}

// ---------------------------------------------------------------------------
extern "C" void kernel_launch(void* const* d_in, const int* in_sizes, int n_in,
                              void* d_out, int out_size, void* d_ws, size_t ws_size,
                              hipStream_t stream)
{
    const float* seq  = (const float*)d_in[0];
    const float* mask = (const float*)d_in[1];
    const float* Wqkv = (const float*)d_in[2];
    const float* W1   = (const float*)d_in[3];
    const float* b1   = (const float*)d_in[4];
    const float* W2   = (const float*)d_in[5];
    const float* b2   = (const float*)d_in[6];
    float* out = (float*)d_out;

    // workspace timeline (proven in round 1):
    //   [0, 50.33M)      : Xf fp32 (QKV out / attn in) -> later hid fp32
    //   [50.33M, 67.11M) : WtQ hi/lo -> (after attn-input ready) att fp32
    //   [33.55M, 50.33M) : Wt1/Wt2 hi/lo (after attn, Xf dead)
    char* base = (char*)d_ws;
    float* Xf   = (float*)base;
    float* hid  = (float*)base;
    float* att  = (float*)(base + 50331648);
    short* WtQh = (short*)(base + 50331648);
    short* WtQl = WtQh + (size_t)3072 * 1024;
    short* Wt1h = (short*)(base + 33554432);
    short* Wt1l = Wt1h + (size_t)2048 * 1024;
    short* Wt2h = (short*)(base + 41943040);
    short* Wt2l = Wt2h + (size_t)2048 * 1024;

    tsplit_kernel<<<dim3(1024 / 32, 3072 / 32), 256, 0, stream>>>(Wqkv, WtQh, WtQl, 1024, 3072);

    gemm_bf16x3<0><<<dim3(3072 / 128, MTOT / 128), 256, 0, stream>>>(
        seq, WtQh, WtQl, nullptr, Xf, MTOT, 3072, 1024);

    // MFMA flash attention: grid x = (b,h), y = q-block (mask L2 locality)
    attn_mfma<<<dim3(BSZ * NHEAD, SEQ / 128), 256, 0, stream>>>(Xf, mask, att);

    tsplit_kernel<<<dim3(1024 / 32, 2048 / 32), 256, 0, stream>>>(W1, Wt1h, Wt1l, 1024, 2048);
    tsplit_kernel<<<dim3(2048 / 32, 1024 / 32), 256, 0, stream>>>(W2, Wt2h, Wt2l, 2048, 1024);

    gemm_bf16x3<1><<<dim3(2048 / 128, MTOT / 128), 256, 0, stream>>>(
        att, Wt1h, Wt1l, b1, hid, MTOT, 2048, 1024);

    gemm_bf16x3<0><<<dim3(1024 / 128, MTOT / 128), 256, 0, stream>>>(
        hid, Wt2h, Wt2l, b2, out, MTOT, 1024, 2048);
}

// Round 4
// 536.348 us; speedup vs baseline: 2.9867x; 1.3416x over previous
//
#include <hip/hip_runtime.h>
#include <math.h>

#define SEQ   2048
#define NHEAD 16
#define HD    64
#define BSZ   2
#define MTOT  (BSZ*SEQ)   // 4096

typedef __bf16 bf16x8 __attribute__((ext_vector_type(8)));
typedef short  s16x8  __attribute__((ext_vector_type(8)));
typedef short  s16x4  __attribute__((ext_vector_type(4)));
typedef float  f32x4  __attribute__((ext_vector_type(4)));

// round-to-nearest-even fp32 -> bf16 (raw short)
__device__ __forceinline__ short f2bf(float x) {
    unsigned u = __builtin_bit_cast(unsigned, x);
    u = (u + 0x7fffu + ((u >> 16) & 1u)) >> 16;
    return (short)u;
}
__device__ __forceinline__ float bf2f(short h) {
    unsigned u = ((unsigned)(unsigned short)h) << 16;
    return __builtin_bit_cast(float, u);
}

// async global->LDS 16B: dest = wave-uniform lds base + lane*16
__device__ __forceinline__ void gl_lds16(const short* g, short* l) {
    __builtin_amdgcn_global_load_lds(
        (const __attribute__((address_space(1))) unsigned int*)g,
        (__attribute__((address_space(3))) unsigned int*)l, 16, 0, 0);
}

// ---------------------------------------------------------------------------
// Transpose + split: W[K,N] fp32 -> Th[N,K], Tl[N,K] bf16 hi/lo
// ---------------------------------------------------------------------------
__global__ __launch_bounds__(256)
void tsplit_kernel(const float* __restrict__ W, short* __restrict__ Th,
                   short* __restrict__ Tl, int K, int N)
{
    __shared__ float T[32][33];
    const int t  = threadIdx.x;
    const int k0 = blockIdx.x * 32;
    const int n0 = blockIdx.y * 32;
    {
        const int kl = t >> 3;
        const int nl = (t & 7) * 4;
        const float4 v = *(const float4*)&W[(size_t)(k0 + kl) * N + n0 + nl];
        T[nl + 0][kl] = v.x; T[nl + 1][kl] = v.y;
        T[nl + 2][kl] = v.z; T[nl + 3][kl] = v.w;
    }
    __syncthreads();
    {
        const int nl = t >> 3;
        const int kl = (t & 7) * 4;
        s16x4 h, l;
        #pragma unroll
        for (int c = 0; c < 4; ++c) {
            const float x = T[nl][kl + c];
            const short hb = f2bf(x);
            h[c] = hb;
            l[c] = f2bf(x - bf2f(hb));
        }
        const size_t o = (size_t)(n0 + nl) * K + k0 + kl;
        *(s16x4*)&Th[o] = h;
        *(s16x4*)&Tl[o] = l;
    }
}

// ---------------------------------------------------------------------------
// bf16x3 split MFMA GEMM v2.
// AMODE 0: A fp32 (convert in staging, padded LDS stride 40).
// AMODE 1: A pre-split bf16 hi/lo via global_load_lds (unpadded, XOR swizzle).
// B always pre-split [N,K] hi/lo via global_load_lds.
// OSPLIT 1: write C as bf16 hi/lo pair; 0: fp32. ACT 1: SiLU before split.
// Block 128x128, BK=32, 4 waves x 4x4 frags of mfma_f32_16x16x32_bf16.
// Swizzle: LDS slot (row, g16) holds global granule g16 ^ ((row>>1)&3).
// ---------------------------------------------------------------------------
template<int AMODE, int ACT, int OSPLIT>
__global__ __launch_bounds__(256, 2)
void gemm2(const float* __restrict__ Af,
           const short* __restrict__ Ahg, const short* __restrict__ Alg,
           const short* __restrict__ Bhg, const short* __restrict__ Blg,
           const float* __restrict__ bias,
           float* __restrict__ Cf, short* __restrict__ Chg, short* __restrict__ Clg,
           int M, int N, int K)
{
    constexpr int ALDA = AMODE ? 32 : 40;
    __shared__ short AhL[128 * ALDA];
    __shared__ short AlL[128 * ALDA];
    __shared__ short BhL[128 * 32];
    __shared__ short BlL[128 * 32];

    const int t    = threadIdx.x;
    const int m0   = blockIdx.y * 128;
    const int n0   = blockIdx.x * 128;
    const int wave = t >> 6;
    const int lane = t & 63;
    const int r    = lane & 15;
    const int qd   = lane >> 4;
    const int wm   = (wave & 1) * 64;
    const int wn   = (wave >> 1) * 64;

    f32x4 acc[4][4];
    #pragma unroll
    for (int i = 0; i < 4; ++i)
        #pragma unroll
        for (int j = 0; j < 4; ++j) acc[i][j] = (f32x4){0.f, 0.f, 0.f, 0.f};

    // AMODE0 staging maps (round-2 proven)
    const int a_row = t >> 3;      // 0..31 (+s*32)
    const int a_g   = t & 7;
    float4 areg[4];
    if (AMODE == 0) {
        #pragma unroll
        for (int s = 0; s < 4; ++s)
            areg[s] = *(const float4*)&Af[(size_t)(m0 + a_row + s * 32) * K + a_g * 4];
    }

    for (int k0 = 0; k0 < K; k0 += 32) {
        __syncthreads();
        // ---- stage B (and A if presplit) via global_load_lds ----
        #pragma unroll
        for (int s = 0; s < 2; ++s) {
            const int p    = wave * 2 + s;
            const int srow = p * 16 + (lane >> 2);
            const int sg   = (lane & 3) ^ ((srow >> 1) & 3);
            const size_t gb = (size_t)(n0 + srow) * K + k0 + sg * 8;
            gl_lds16(&Bhg[gb], &BhL[p * 512]);
            gl_lds16(&Blg[gb], &BlL[p * 512]);
            if (AMODE == 1) {
                const size_t ga = (size_t)(m0 + srow) * K + k0 + sg * 8;
                gl_lds16(&Ahg[ga], &AhL[p * 512]);
                gl_lds16(&Alg[ga], &AlL[p * 512]);
            }
        }
        if (AMODE == 0) {
            // convert prefetched fp32 A -> hi/lo, padded layout
            #pragma unroll
            for (int s = 0; s < 4; ++s) {
                const float4 v = areg[s];
                const float xs[4] = {v.x, v.y, v.z, v.w};
                s16x4 h, l;
                #pragma unroll
                for (int c = 0; c < 4; ++c) {
                    const short hb = f2bf(xs[c]);
                    h[c] = hb;
                    l[c] = f2bf(xs[c] - bf2f(hb));
                }
                const int off = (a_row + s * 32) * 40 + a_g * 4;
                *(s16x4*)&AhL[off] = h;
                *(s16x4*)&AlL[off] = l;
            }
        }
        __syncthreads();

        if (AMODE == 0) {
            const int kn = (k0 + 32 < K) ? (k0 + 32) : 0;
            #pragma unroll
            for (int s = 0; s < 4; ++s)
                areg[s] = *(const float4*)&Af[(size_t)(m0 + a_row + s * 32) * K + kn + a_g * 4];
        }

        // ---- fragment loads ----
        bf16x8 afh[4], afl[4], bfh[4], bfl[4];
        #pragma unroll
        for (int i = 0; i < 4; ++i) {
            const int row = wm + i * 16 + r;
            const int oa = AMODE ? row * 32 + ((qd ^ ((row >> 1) & 3)) * 8)
                                 : row * 40 + qd * 8;
            afh[i] = __builtin_bit_cast(bf16x8, *(const s16x8*)&AhL[oa]);
            afl[i] = __builtin_bit_cast(bf16x8, *(const s16x8*)&AlL[oa]);
        }
        #pragma unroll
        for (int j = 0; j < 4; ++j) {
            const int row = wn + j * 16 + r;
            const int ob = row * 32 + ((qd ^ ((row >> 1) & 3)) * 8);
            bfh[j] = __builtin_bit_cast(bf16x8, *(const s16x8*)&BhL[ob]);
            bfl[j] = __builtin_bit_cast(bf16x8, *(const s16x8*)&BlL[ob]);
        }

        #pragma unroll
        for (int i = 0; i < 4; ++i)
            #pragma unroll
            for (int j = 0; j < 4; ++j) {
                acc[i][j] = __builtin_amdgcn_mfma_f32_16x16x32_bf16(afh[i], bfh[j], acc[i][j], 0, 0, 0);
                acc[i][j] = __builtin_amdgcn_mfma_f32_16x16x32_bf16(afh[i], bfl[j], acc[i][j], 0, 0, 0);
                acc[i][j] = __builtin_amdgcn_mfma_f32_16x16x32_bf16(afl[i], bfh[j], acc[i][j], 0, 0, 0);
            }
    }

    // ---- epilogue: C/D layout col=lane&15, row=quad*4+g ----
    #pragma unroll
    for (int i = 0; i < 4; ++i)
        #pragma unroll
        for (int j = 0; j < 4; ++j) {
            const int col = n0 + wn + j * 16 + r;
            const float bv = bias ? bias[col] : 0.f;
            #pragma unroll
            for (int g = 0; g < 4; ++g) {
                const int row = m0 + wm + i * 16 + qd * 4 + g;
                float x = acc[i][j][g] + bv;
                if (ACT == 1) x = x / (1.0f + __expf(-x));
                if (OSPLIT) {
                    const short hb = f2bf(x);
                    Chg[(size_t)row * N + col] = hb;
                    Clg[(size_t)row * N + col] = f2bf(x - bf2f(hb));
                } else {
                    Cf[(size_t)row * N + col] = x;
                }
            }
        }
}

// ---------------------------------------------------------------------------
// MFMA flash attention v2: inputs pre-split Xh/Xl bf16 [4096,3072].
// Block: 128 q-rows x one (b,h); 4 waves; K-tile 64.
// K staged via global_load_lds (swizzle g^=(row&7)); V transposed via short
// copies (swizzle g^=(d&7)); P wave-private swizzled (g^=(row>>1)&7).
// Outputs split atth/attl. Scale 1/8 applied in softmax (exact pow2).
// ---------------------------------------------------------------------------
__global__ __launch_bounds__(256, 2)
void attn_mfma2(const short* __restrict__ Xh, const short* __restrict__ Xl,
                const float* __restrict__ mask,
                short* __restrict__ atth, short* __restrict__ attl)
{
    __shared__ short KhL[64 * 64];
    __shared__ short KlL[64 * 64];
    __shared__ short VhL[64 * 64];   // [d][key] swizzled
    __shared__ short VlL[64 * 64];
    __shared__ short PhL[128 * 64];  // wave-private rows
    __shared__ short PlL[128 * 64];

    const int t    = threadIdx.x;
    const int lane = t & 63;
    const int w    = t >> 6;
    const int r    = lane & 15;
    const int qd   = lane >> 4;
    const int b    = blockIdx.x >> 4;
    const int h    = blockIdx.x & 15;
    const int q0   = blockIdx.y * 128;

    // ---- Q fragments straight from global (no conversion) ----
    bf16x8 qh[2][2], ql[2][2];
    #pragma unroll
    for (int i = 0; i < 2; ++i) {
        const size_t qoff = (size_t)(b * SEQ + q0 + w * 32 + i * 16 + r) * 3072 + h * 64;
        #pragma unroll
        for (int ks = 0; ks < 2; ++ks) {
            qh[i][ks] = __builtin_bit_cast(bf16x8, *(const s16x8*)&Xh[qoff + ks * 32 + qd * 8]);
            ql[i][ks] = __builtin_bit_cast(bf16x8, *(const s16x8*)&Xl[qoff + ks * 32 + qd * 8]);
        }
    }

    // V staging map
    const int vc = t & 63;           // key index
    const int vg = (t >> 6) * 16;    // d base

    f32x4 O[2][4];
    #pragma unroll
    for (int i = 0; i < 2; ++i)
        #pragma unroll
        for (int j = 0; j < 4; ++j) O[i][j] = (f32x4){0.f, 0.f, 0.f, 0.f};
    float m_i[2][4], l_i[2][4];
    #pragma unroll
    for (int i = 0; i < 2; ++i)
        #pragma unroll
        for (int g = 0; g < 4; ++g) { m_i[i][g] = -1e30f; l_i[i][g] = 0.f; }

    for (int kt = 0; kt < SEQ / 64; ++kt) {
        const int k0   = kt * 64;
        const int tok0 = b * SEQ + k0;

        __syncthreads();   // all waves done with prior K/V
        // ---- stage K via global_load_lds (rows of 128B = 8 granules) ----
        #pragma unroll
        for (int s = 0; s < 2; ++s) {
            const int p    = w * 2 + s;
            const int srow = p * 8 + (lane >> 3);
            const int sg   = (lane & 7) ^ (srow & 7);
            const size_t gk = (size_t)(tok0 + srow) * 3072 + 1024 + h * 64 + sg * 8;
            gl_lds16(&Xh[gk], &KhL[p * 512]);
            gl_lds16(&Xl[gk], &KlL[p * 512]);
        }
        // ---- stage V transposed [d][key], short copies ----
        {
            const size_t vb = (size_t)(tok0 + vc) * 3072 + 2048 + h * 64;
            #pragma unroll
            for (int s = 0; s < 4; ++s) {
                const int d0 = vg + s * 4;
                const s16x4 vh = *(const s16x4*)&Xh[vb + d0];
                const s16x4 vl = *(const s16x4*)&Xl[vb + d0];
                #pragma unroll
                for (int c = 0; c < 4; ++c) {
                    const int d = d0 + c;
                    const int off = d * 64 + (((vc >> 3) ^ (d & 7)) * 8) + (vc & 7);
                    VhL[off] = vh[c];
                    VlL[off] = vl[c];
                }
            }
        }
        __syncthreads();

        // mask prefetch
        float mreg[2][4][4];
        #pragma unroll
        for (int i = 0; i < 2; ++i)
            #pragma unroll
            for (int g = 0; g < 4; ++g) {
                const size_t mrow = (size_t)(q0 + w * 32 + i * 16 + qd * 4 + g) * SEQ + k0;
                #pragma unroll
                for (int j = 0; j < 4; ++j)
                    mreg[i][g][j] = mask[mrow + j * 16 + r];
            }

        // ---- S = Q @ K^T ----
        f32x4 S[2][4];
        #pragma unroll
        for (int i = 0; i < 2; ++i)
            #pragma unroll
            for (int j = 0; j < 4; ++j) S[i][j] = (f32x4){0.f, 0.f, 0.f, 0.f};
        #pragma unroll
        for (int ks = 0; ks < 2; ++ks) {
            bf16x8 kfh[4], kfl[4];
            #pragma unroll
            for (int j = 0; j < 4; ++j) {
                const int row = j * 16 + r;
                const int off = row * 64 + (((ks * 4 + qd) ^ (row & 7)) * 8);
                kfh[j] = __builtin_bit_cast(bf16x8, *(const s16x8*)&KhL[off]);
                kfl[j] = __builtin_bit_cast(bf16x8, *(const s16x8*)&KlL[off]);
            }
            #pragma unroll
            for (int i = 0; i < 2; ++i)
                #pragma unroll
                for (int j = 0; j < 4; ++j) {
                    S[i][j] = __builtin_amdgcn_mfma_f32_16x16x32_bf16(qh[i][ks], kfh[j], S[i][j], 0, 0, 0);
                    S[i][j] = __builtin_amdgcn_mfma_f32_16x16x32_bf16(qh[i][ks], kfl[j], S[i][j], 0, 0, 0);
                    S[i][j] = __builtin_amdgcn_mfma_f32_16x16x32_bf16(ql[i][ks], kfh[j], S[i][j], 0, 0, 0);
                }
        }

        // ---- scale+mask + online softmax (registers + quad shfl) ----
        #pragma unroll
        for (int i = 0; i < 2; ++i)
            #pragma unroll
            for (int g = 0; g < 4; ++g) {
                float sv[4];
                #pragma unroll
                for (int j = 0; j < 4; ++j) sv[j] = fmaf(S[i][j][g], 0.125f, mreg[i][g][j]);
                float mx = fmaxf(fmaxf(sv[0], sv[1]), fmaxf(sv[2], sv[3]));
                mx = fmaxf(mx, __shfl_xor(mx, 1));
                mx = fmaxf(mx, __shfl_xor(mx, 2));
                mx = fmaxf(mx, __shfl_xor(mx, 4));
                mx = fmaxf(mx, __shfl_xor(mx, 8));
                const float mnew  = fmaxf(m_i[i][g], mx);
                const float alpha = __expf(m_i[i][g] - mnew);
                float rs = 0.f;
                #pragma unroll
                for (int j = 0; j < 4; ++j) {
                    const float p = __expf(sv[j] - mnew);
                    S[i][j][g] = p;
                    rs += p;
                }
                rs += __shfl_xor(rs, 1);
                rs += __shfl_xor(rs, 2);
                rs += __shfl_xor(rs, 4);
                rs += __shfl_xor(rs, 8);
                l_i[i][g] = l_i[i][g] * alpha + rs;
                m_i[i][g] = mnew;
                #pragma unroll
                for (int j = 0; j < 4; ++j) O[i][j][g] *= alpha;
            }

        // ---- P -> LDS (wave-private rows; no barrier needed) ----
        #pragma unroll
        for (int i = 0; i < 2; ++i)
            #pragma unroll
            for (int j = 0; j < 4; ++j)
                #pragma unroll
                for (int g = 0; g < 4; ++g) {
                    const int prow = w * 32 + i * 16 + qd * 4 + g;
                    const int gr   = (j * 2 + (r >> 3)) ^ ((prow >> 1) & 7);
                    const int off  = prow * 64 + gr * 8 + (r & 7);
                    const float p  = S[i][j][g];
                    const short ph = f2bf(p);
                    PhL[off] = ph;
                    PlL[off] = f2bf(p - bf2f(ph));
                }

        // ---- O += P @ V ----
        #pragma unroll
        for (int ks = 0; ks < 2; ++ks) {
            bf16x8 pfh[2], pfl[2], vfh[4], vfl[4];
            #pragma unroll
            for (int i = 0; i < 2; ++i) {
                const int row = w * 32 + i * 16 + r;
                const int off = row * 64 + (((ks * 4 + qd) ^ ((row >> 1) & 7)) * 8);
                pfh[i] = __builtin_bit_cast(bf16x8, *(const s16x8*)&PhL[off]);
                pfl[i] = __builtin_bit_cast(bf16x8, *(const s16x8*)&PlL[off]);
            }
            #pragma unroll
            for (int j = 0; j < 4; ++j) {
                const int row = j * 16 + r;
                const int off = row * 64 + (((ks * 4 + qd) ^ (row & 7)) * 8);
                vfh[j] = __builtin_bit_cast(bf16x8, *(const s16x8*)&VhL[off]);
                vfl[j] = __builtin_bit_cast(bf16x8, *(const s16x8*)&VlL[off]);
            }
            #pragma unroll
            for (int i = 0; i < 2; ++i)
                #pragma unroll
                for (int j = 0; j < 4; ++j) {
                    O[i][j] = __builtin_amdgcn_mfma_f32_16x16x32_bf16(pfh[i], vfh[j], O[i][j], 0, 0, 0);
                    O[i][j] = __builtin_amdgcn_mfma_f32_16x16x32_bf16(pfh[i], vfl[j], O[i][j], 0, 0, 0);
                    O[i][j] = __builtin_amdgcn_mfma_f32_16x16x32_bf16(pfl[i], vfh[j], O[i][j], 0, 0, 0);
                }
        }
    }

    // ---- epilogue: normalize + split store ----
    #pragma unroll
    for (int i = 0; i < 2; ++i)
        #pragma unroll
        for (int g = 0; g < 4; ++g) {
            const float inv = 1.0f / l_i[i][g];
            const size_t row = (size_t)(b * SEQ + q0 + w * 32 + i * 16 + qd * 4 + g);
            #pragma unroll
            for (int j = 0; j < 4; ++j) {
                const float x = O[i][j][g] * inv;
                const short hb = f2bf(x);
                const size_t o = row * 1024 + h * 64 + j * 16 + r;
                atth[o] = hb;
                attl[o] = f2bf(x - bf2f(hb));
            }
        }
}

// ---------------------------------------------------------------------------
extern "C" void kernel_launch(void* const* d_in, const int* in_sizes, int n_in,
                              void* d_out, int out_size, void* d_ws, size_t ws_size,
                              hipStream_t stream)
{
    const float* seq  = (const float*)d_in[0];
    const float* mask = (const float*)d_in[1];
    const float* Wqkv = (const float*)d_in[2];
    const float* W1   = (const float*)d_in[3];
    const float* b1   = (const float*)d_in[4];
    const float* W2   = (const float*)d_in[5];
    const float* b2   = (const float*)d_in[6];
    float* out = (float*)d_out;

    // workspace timeline (peak exactly 64 MiB):
    //  P0: WtQ [48,60)
    //  P1: QKV gemm: Xh [0,24), Xl [24,48)         (reads seq + WtQ)
    //  P2: attn: atth [48,56), attl [56,64)        (WtQ dead)
    //  P3: Wt1 [0,8), Wt2 [8,16)                   (X dead)
    //  P4: FFN1: hidh [16,32), hidl [32,48)
    //  P5: FFN2 -> out
    const size_t MiB = 1048576;
    char* B = (char*)d_ws;
    short* Xh   = (short*)(B + 0);
    short* Xl   = (short*)(B + 24 * MiB);
    short* WtQh = (short*)(B + 48 * MiB);
    short* WtQl = (short*)(B + 54 * MiB);
    short* atth = (short*)(B + 48 * MiB);
    short* attl = (short*)(B + 56 * MiB);
    short* Wt1h = (short*)(B + 0);
    short* Wt1l = (short*)(B + 4 * MiB);
    short* Wt2h = (short*)(B + 8 * MiB);
    short* Wt2l = (short*)(B + 12 * MiB);
    short* hidh = (short*)(B + 16 * MiB);
    short* hidl = (short*)(B + 32 * MiB);

    tsplit_kernel<<<dim3(1024 / 32, 3072 / 32), 256, 0, stream>>>(Wqkv, WtQh, WtQl, 1024, 3072);

    // QKV: A=seq fp32 (convert path), B=WtQ presplit, out split Xh/Xl
    gemm2<0, 0, 1><<<dim3(3072 / 128, MTOT / 128), 256, 0, stream>>>(
        seq, nullptr, nullptr, WtQh, WtQl, nullptr, nullptr, Xh, Xl, MTOT, 3072, 1024);

    attn_mfma2<<<dim3(BSZ * NHEAD, SEQ / 128), 256, 0, stream>>>(Xh, Xl, mask, atth, attl);

    tsplit_kernel<<<dim3(1024 / 32, 2048 / 32), 256, 0, stream>>>(W1, Wt1h, Wt1l, 1024, 2048);
    tsplit_kernel<<<dim3(2048 / 32, 1024 / 32), 256, 0, stream>>>(W2, Wt2h, Wt2l, 2048, 1024);

    // FFN1: A=att presplit, SiLU, out split hid
    gemm2<1, 1, 1><<<dim3(2048 / 128, MTOT / 128), 256, 0, stream>>>(
        nullptr, atth, attl, Wt1h, Wt1l, b1, nullptr, hidh, hidl, MTOT, 2048, 1024);

    // FFN2: A=hid presplit, +bias, out fp32
    gemm2<1, 0, 0><<<dim3(1024 / 128, MTOT / 128), 256, 0, stream>>>(
        nullptr, hidh, hidl, Wt2h, Wt2l, b2, out, nullptr, nullptr, MTOT, 1024, 2048);
}

// Round 5
// 408.865 us; speedup vs baseline: 3.9179x; 1.3118x over previous
//
#include <hip/hip_runtime.h>
#include <math.h>

#define SEQ   2048
#define NHEAD 16
#define HD    64
#define BSZ   2
#define MTOT  (BSZ*SEQ)   // 4096

typedef __bf16 bf16x8 __attribute__((ext_vector_type(8)));
typedef short  s16x8  __attribute__((ext_vector_type(8)));
typedef short  s16x4  __attribute__((ext_vector_type(4)));
typedef float  f32x4  __attribute__((ext_vector_type(4)));

// round-to-nearest-even fp32 -> bf16 (raw short)
__device__ __forceinline__ short f2bf(float x) {
    unsigned u = __builtin_bit_cast(unsigned, x);
    u = (u + 0x7fffu + ((u >> 16) & 1u)) >> 16;
    return (short)u;
}
__device__ __forceinline__ float bf2f(short h) {
    unsigned u = ((unsigned)(unsigned short)h) << 16;
    return __builtin_bit_cast(float, u);
}

// async global->LDS 16B: dest = wave-uniform lds base + lane*16
__device__ __forceinline__ void gl_lds16(const short* g, short* l) {
    __builtin_amdgcn_global_load_lds(
        (const __attribute__((address_space(1))) unsigned int*)g,
        (__attribute__((address_space(3))) unsigned int*)l, 16, 0, 0);
}

// ---------------------------------------------------------------------------
// Transpose + split: W[K,N] fp32 -> Th[N,K], Tl[N,K] bf16 hi/lo
// ---------------------------------------------------------------------------
__global__ __launch_bounds__(256)
void tsplit_kernel(const float* __restrict__ W, short* __restrict__ Th,
                   short* __restrict__ Tl, int K, int N)
{
    __shared__ float T[32][33];
    const int t  = threadIdx.x;
    const int k0 = blockIdx.x * 32;
    const int n0 = blockIdx.y * 32;
    {
        const int kl = t >> 3;
        const int nl = (t & 7) * 4;
        const float4 v = *(const float4*)&W[(size_t)(k0 + kl) * N + n0 + nl];
        T[nl + 0][kl] = v.x; T[nl + 1][kl] = v.y;
        T[nl + 2][kl] = v.z; T[nl + 3][kl] = v.w;
    }
    __syncthreads();
    {
        const int nl = t >> 3;
        const int kl = (t & 7) * 4;
        s16x4 h, l;
        #pragma unroll
        for (int c = 0; c < 4; ++c) {
            const float x = T[nl][kl + c];
            const short hb = f2bf(x);
            h[c] = hb;
            l[c] = f2bf(x - bf2f(hb));
        }
        const size_t o = (size_t)(n0 + nl) * K + k0 + kl;
        *(s16x4*)&Th[o] = h;
        *(s16x4*)&Tl[o] = l;
    }
}

// ---------------------------------------------------------------------------
// bf16x3 split MFMA GEMM v2 (round-4 proven) + VT epilogue option.
// VT=1 (QKV only): cols<2048 -> Chg/Clg [row][col] stride NOUT=2048;
//                  cols>=2048 -> V^T hi-only store Vtg[(col-2048)*4096 + row].
// ---------------------------------------------------------------------------
template<int AMODE, int ACT, int OSPLIT, int VT>
__global__ __launch_bounds__(256, 2)
void gemm2(const float* __restrict__ Af,
           const short* __restrict__ Ahg, const short* __restrict__ Alg,
           const short* __restrict__ Bhg, const short* __restrict__ Blg,
           const float* __restrict__ bias,
           float* __restrict__ Cf, short* __restrict__ Chg, short* __restrict__ Clg,
           short* __restrict__ Vtg,
           int M, int N, int K, int NOUT)
{
    constexpr int ALDA = AMODE ? 32 : 40;
    __shared__ short AhL[128 * ALDA];
    __shared__ short AlL[128 * ALDA];
    __shared__ short BhL[128 * 32];
    __shared__ short BlL[128 * 32];

    const int t    = threadIdx.x;
    const int m0   = blockIdx.y * 128;
    const int n0   = blockIdx.x * 128;
    const int wave = t >> 6;
    const int lane = t & 63;
    const int r    = lane & 15;
    const int qd   = lane >> 4;
    const int wm   = (wave & 1) * 64;
    const int wn   = (wave >> 1) * 64;

    f32x4 acc[4][4];
    #pragma unroll
    for (int i = 0; i < 4; ++i)
        #pragma unroll
        for (int j = 0; j < 4; ++j) acc[i][j] = (f32x4){0.f, 0.f, 0.f, 0.f};

    const int a_row = t >> 3;
    const int a_g   = t & 7;
    float4 areg[4];
    if (AMODE == 0) {
        #pragma unroll
        for (int s = 0; s < 4; ++s)
            areg[s] = *(const float4*)&Af[(size_t)(m0 + a_row + s * 32) * K + a_g * 4];
    }

    for (int k0 = 0; k0 < K; k0 += 32) {
        __syncthreads();
        #pragma unroll
        for (int s = 0; s < 2; ++s) {
            const int p    = wave * 2 + s;
            const int srow = p * 16 + (lane >> 2);
            const int sg   = (lane & 3) ^ ((srow >> 1) & 3);
            const size_t gb = (size_t)(n0 + srow) * K + k0 + sg * 8;
            gl_lds16(&Bhg[gb], &BhL[p * 512]);
            gl_lds16(&Blg[gb], &BlL[p * 512]);
            if (AMODE == 1) {
                const size_t ga = (size_t)(m0 + srow) * K + k0 + sg * 8;
                gl_lds16(&Ahg[ga], &AhL[p * 512]);
                gl_lds16(&Alg[ga], &AlL[p * 512]);
            }
        }
        if (AMODE == 0) {
            #pragma unroll
            for (int s = 0; s < 4; ++s) {
                const float4 v = areg[s];
                const float xs[4] = {v.x, v.y, v.z, v.w};
                s16x4 h, l;
                #pragma unroll
                for (int c = 0; c < 4; ++c) {
                    const short hb = f2bf(xs[c]);
                    h[c] = hb;
                    l[c] = f2bf(xs[c] - bf2f(hb));
                }
                const int off = (a_row + s * 32) * 40 + a_g * 4;
                *(s16x4*)&AhL[off] = h;
                *(s16x4*)&AlL[off] = l;
            }
        }
        __syncthreads();

        if (AMODE == 0) {
            const int kn = (k0 + 32 < K) ? (k0 + 32) : 0;
            #pragma unroll
            for (int s = 0; s < 4; ++s)
                areg[s] = *(const float4*)&Af[(size_t)(m0 + a_row + s * 32) * K + kn + a_g * 4];
        }

        bf16x8 afh[4], afl[4], bfh[4], bfl[4];
        #pragma unroll
        for (int i = 0; i < 4; ++i) {
            const int row = wm + i * 16 + r;
            const int oa = AMODE ? row * 32 + ((qd ^ ((row >> 1) & 3)) * 8)
                                 : row * 40 + qd * 8;
            afh[i] = __builtin_bit_cast(bf16x8, *(const s16x8*)&AhL[oa]);
            afl[i] = __builtin_bit_cast(bf16x8, *(const s16x8*)&AlL[oa]);
        }
        #pragma unroll
        for (int j = 0; j < 4; ++j) {
            const int row = wn + j * 16 + r;
            const int ob = row * 32 + ((qd ^ ((row >> 1) & 3)) * 8);
            bfh[j] = __builtin_bit_cast(bf16x8, *(const s16x8*)&BhL[ob]);
            bfl[j] = __builtin_bit_cast(bf16x8, *(const s16x8*)&BlL[ob]);
        }

        #pragma unroll
        for (int i = 0; i < 4; ++i)
            #pragma unroll
            for (int j = 0; j < 4; ++j) {
                acc[i][j] = __builtin_amdgcn_mfma_f32_16x16x32_bf16(afh[i], bfh[j], acc[i][j], 0, 0, 0);
                acc[i][j] = __builtin_amdgcn_mfma_f32_16x16x32_bf16(afh[i], bfl[j], acc[i][j], 0, 0, 0);
                acc[i][j] = __builtin_amdgcn_mfma_f32_16x16x32_bf16(afl[i], bfh[j], acc[i][j], 0, 0, 0);
            }
    }

    #pragma unroll
    for (int i = 0; i < 4; ++i)
        #pragma unroll
        for (int j = 0; j < 4; ++j) {
            const int col = n0 + wn + j * 16 + r;
            if (VT && col >= 2048) {
                // V^T hi-only store: Vtg[(col-2048)*4096 + row], 4 rows packed
                const int f = col - 2048;
                s16x4 hv;
                #pragma unroll
                for (int g = 0; g < 4; ++g) hv[g] = f2bf(acc[i][j][g]);
                const int row0 = m0 + wm + i * 16 + qd * 4;
                *(s16x4*)&Vtg[(size_t)f * 4096 + row0] = hv;
            } else {
                const float bv = bias ? bias[col] : 0.f;
                #pragma unroll
                for (int g = 0; g < 4; ++g) {
                    const int row = m0 + wm + i * 16 + qd * 4 + g;
                    float x = acc[i][j][g] + bv;
                    if (ACT == 1) x = x / (1.0f + __expf(-x));
                    if (OSPLIT) {
                        const short hb = f2bf(x);
                        Chg[(size_t)row * NOUT + col] = hb;
                        Clg[(size_t)row * NOUT + col] = f2bf(x - bf2f(hb));
                    } else {
                        Cf[(size_t)row * NOUT + col] = x;
                    }
                }
            }
        }
}

// ---------------------------------------------------------------------------
// MFMA flash attention v3.
// Inputs: Xh/Xl [4096][2048] = Q|K presplit; Vth [1024][4096] = V^T bf16.
// Fixed-offset softmax (p = exp(s-16), exact softmax in fp32 range, no
// running max / rescale). Row-sum l via mfma(P, ones) -> every lane.
// K/V double-buffered via global_load_lds; ONE barrier per tile; next tile's
// loads issued right after the barrier so the vmcnt drain is a full tile old.
// P single-bf16, wave-private LDS rows. LDS = 64 KB.
// ---------------------------------------------------------------------------
__global__ __launch_bounds__(256, 2)
void attn_mfma3(const short* __restrict__ Xh, const short* __restrict__ Xl,
                const short* __restrict__ Vth, const float* __restrict__ mask,
                short* __restrict__ atth, short* __restrict__ attl)
{
    __shared__ short KhL[2 * 64 * 64];   // 16 KB (two buffers)
    __shared__ short KlL[2 * 64 * 64];   // 16 KB
    __shared__ short VhL[2 * 64 * 64];   // 16 KB  [d][key]
    __shared__ short PhL[128 * 64];      // 16 KB  wave-private rows

    const int t    = threadIdx.x;
    const int lane = t & 63;
    const int w    = t >> 6;
    const int r    = lane & 15;
    const int qd   = lane >> 4;
    const int b    = blockIdx.x >> 4;
    const int h    = blockIdx.x & 15;
    const int q0   = blockIdx.y * 128;

    // staging map (per wave: issues p = 2w, 2w+1; each covers 8 rows)
    const int srow0 = (lane >> 3);        // + p*8
    const int sgx   = lane & 7;

    // ---- Q fragments straight from global ----
    bf16x8 qh[2][2], ql[2][2];
    #pragma unroll
    for (int i = 0; i < 2; ++i) {
        const size_t qoff = (size_t)(b * SEQ + q0 + w * 32 + i * 16 + r) * 2048 + h * 64;
        #pragma unroll
        for (int ks = 0; ks < 2; ++ks) {
            qh[i][ks] = __builtin_bit_cast(bf16x8, *(const s16x8*)&Xh[qoff + ks * 32 + qd * 8]);
            ql[i][ks] = __builtin_bit_cast(bf16x8, *(const s16x8*)&Xl[qoff + ks * 32 + qd * 8]);
        }
    }

    // ones B-fragment (all 1.0 bf16) for the row-sum MFMA
    s16x8 ones_s;
    #pragma unroll
    for (int c = 0; c < 8; ++c) ones_s[c] = (short)0x3F80;
    const bf16x8 ones = __builtin_bit_cast(bf16x8, ones_s);

    f32x4 O[2][4], Lac[2];
    #pragma unroll
    for (int i = 0; i < 2; ++i) {
        Lac[i] = (f32x4){0.f, 0.f, 0.f, 0.f};
        #pragma unroll
        for (int j = 0; j < 4; ++j) O[i][j] = (f32x4){0.f, 0.f, 0.f, 0.f};
    }

    // ---- stage lambda (issues 6 gl_lds16 per wave: Kh,Kl,Vh x2) ----
    auto stage = [&](int kt, int buf) {
        const int k0   = kt * 64;
        const int tok0 = b * SEQ + k0;
        const int bo   = buf * 4096;
        #pragma unroll
        for (int s = 0; s < 2; ++s) {
            const int p    = w * 2 + s;
            const int srow = p * 8 + srow0;
            const int sg   = sgx ^ (srow & 7);
            const size_t gk = (size_t)(tok0 + srow) * 2048 + 1024 + h * 64 + sg * 8;
            gl_lds16(&Xh[gk], &KhL[bo + p * 512]);
            gl_lds16(&Xl[gk], &KlL[bo + p * 512]);
            const size_t gv = (size_t)(h * 64 + srow) * 4096 + (size_t)b * SEQ + k0 + sg * 8;
            gl_lds16(&Vth[gv], &VhL[bo + p * 512]);
        }
    };

    stage(0, 0);   // prologue

    for (int kt = 0; kt < SEQ / 64; ++kt) {
        const int cur = kt & 1;
        const int k0  = kt * 64;

        __syncthreads();   // drains vmcnt: tile-kt loads ready; prior readers of buf (kt+1)&1 done
        if (kt + 1 < SEQ / 64) stage(kt + 1, 1 - cur);

        // mask loads (in flight during S)
        float mreg[2][4][4];
        #pragma unroll
        for (int i = 0; i < 2; ++i)
            #pragma unroll
            for (int g = 0; g < 4; ++g) {
                const size_t mrow = (size_t)(q0 + w * 32 + i * 16 + qd * 4 + g) * SEQ + k0;
                #pragma unroll
                for (int j = 0; j < 4; ++j)
                    mreg[i][g][j] = mask[mrow + j * 16 + r];
            }

        // ---- S = Q @ K^T (3-term) ----
        const int co = cur * 4096;
        f32x4 S[2][4];
        #pragma unroll
        for (int i = 0; i < 2; ++i)
            #pragma unroll
            for (int j = 0; j < 4; ++j) S[i][j] = (f32x4){0.f, 0.f, 0.f, 0.f};
        #pragma unroll
        for (int ks = 0; ks < 2; ++ks) {
            bf16x8 kfh[4], kfl[4];
            #pragma unroll
            for (int j = 0; j < 4; ++j) {
                const int row = j * 16 + r;
                const int off = co + row * 64 + (((ks * 4 + qd) ^ (row & 7)) * 8);
                kfh[j] = __builtin_bit_cast(bf16x8, *(const s16x8*)&KhL[off]);
                kfl[j] = __builtin_bit_cast(bf16x8, *(const s16x8*)&KlL[off]);
            }
            #pragma unroll
            for (int i = 0; i < 2; ++i)
                #pragma unroll
                for (int j = 0; j < 4; ++j) {
                    S[i][j] = __builtin_amdgcn_mfma_f32_16x16x32_bf16(qh[i][ks], kfh[j], S[i][j], 0, 0, 0);
                    S[i][j] = __builtin_amdgcn_mfma_f32_16x16x32_bf16(qh[i][ks], kfl[j], S[i][j], 0, 0, 0);
                    S[i][j] = __builtin_amdgcn_mfma_f32_16x16x32_bf16(ql[i][ks], kfh[j], S[i][j], 0, 0, 0);
                }
        }

        // ---- fixed-offset softmax: p = exp(s/8 + mask - 16) ----
        #pragma unroll
        for (int i = 0; i < 2; ++i)
            #pragma unroll
            for (int j = 0; j < 4; ++j)
                #pragma unroll
                for (int g = 0; g < 4; ++g)
                    S[i][j][g] = __expf(fmaf(S[i][j][g], 0.125f, mreg[i][g][j]) - 16.0f);

        // ---- P -> LDS (bf16, wave-private rows, swizzled) ----
        #pragma unroll
        for (int i = 0; i < 2; ++i)
            #pragma unroll
            for (int j = 0; j < 4; ++j)
                #pragma unroll
                for (int g = 0; g < 4; ++g) {
                    const int prow = w * 32 + i * 16 + qd * 4 + g;
                    const int gr   = (j * 2 + (r >> 3)) ^ ((prow >> 1) & 7);
                    PhL[prow * 64 + gr * 8 + (r & 7)] = f2bf(S[i][j][g]);
                }

        // ---- O += P @ V ; Lac += P @ ones ----
        #pragma unroll
        for (int ks = 0; ks < 2; ++ks) {
            bf16x8 pfh[2], vfh[4];
            #pragma unroll
            for (int i = 0; i < 2; ++i) {
                const int row = w * 32 + i * 16 + r;
                pfh[i] = __builtin_bit_cast(bf16x8,
                    *(const s16x8*)&PhL[row * 64 + (((ks * 4 + qd) ^ ((row >> 1) & 7)) * 8)]);
            }
            #pragma unroll
            for (int j = 0; j < 4; ++j) {
                const int row = j * 16 + r;
                vfh[j] = __builtin_bit_cast(bf16x8,
                    *(const s16x8*)&VhL[co + row * 64 + (((ks * 4 + qd) ^ (row & 7)) * 8)]);
            }
            #pragma unroll
            for (int i = 0; i < 2; ++i) {
                Lac[i] = __builtin_amdgcn_mfma_f32_16x16x32_bf16(pfh[i], ones, Lac[i], 0, 0, 0);
                #pragma unroll
                for (int j = 0; j < 4; ++j)
                    O[i][j] = __builtin_amdgcn_mfma_f32_16x16x32_bf16(pfh[i], vfh[j], O[i][j], 0, 0, 0);
            }
        }
    }

    // ---- epilogue: normalize + split store ----
    #pragma unroll
    for (int i = 0; i < 2; ++i)
        #pragma unroll
        for (int g = 0; g < 4; ++g) {
            const float inv = 1.0f / Lac[i][g];
            const size_t row = (size_t)(b * SEQ + q0 + w * 32 + i * 16 + qd * 4 + g);
            #pragma unroll
            for (int j = 0; j < 4; ++j) {
                const float x = O[i][j][g] * inv;
                const short hb = f2bf(x);
                const size_t o = row * 1024 + h * 64 + j * 16 + r;
                atth[o] = hb;
                attl[o] = f2bf(x - bf2f(hb));
            }
        }
}

// ---------------------------------------------------------------------------
extern "C" void kernel_launch(void* const* d_in, const int* in_sizes, int n_in,
                              void* d_out, int out_size, void* d_ws, size_t ws_size,
                              hipStream_t stream)
{
    const float* seq  = (const float*)d_in[0];
    const float* mask = (const float*)d_in[1];
    const float* Wqkv = (const float*)d_in[2];
    const float* W1   = (const float*)d_in[3];
    const float* b1   = (const float*)d_in[4];
    const float* W2   = (const float*)d_in[5];
    const float* b2   = (const float*)d_in[6];
    float* out = (float*)d_out;

    // workspace (peak 64 MiB):
    //  P1: Xh [0,16), Xl [16,32), Vth [32,40), WtQh [48,54), WtQl [54,60)
    //  P2 attn (WtQ dead): atth [48,56), attl [56,64)
    //  P3 FFN (X,Vt dead): Wt1 [0,8), Wt2 [8,16), hidh [16,32), hidl [32,48)
    const size_t MiB = 1048576;
    char* B = (char*)d_ws;
    short* Xh   = (short*)(B + 0);
    short* Xl   = (short*)(B + 16 * MiB);
    short* Vth  = (short*)(B + 32 * MiB);
    short* WtQh = (short*)(B + 48 * MiB);
    short* WtQl = (short*)(B + 54 * MiB);
    short* atth = (short*)(B + 48 * MiB);
    short* attl = (short*)(B + 56 * MiB);
    short* Wt1h = (short*)(B + 0);
    short* Wt1l = (short*)(B + 4 * MiB);
    short* Wt2h = (short*)(B + 8 * MiB);
    short* Wt2l = (short*)(B + 12 * MiB);
    short* hidh = (short*)(B + 16 * MiB);
    short* hidl = (short*)(B + 32 * MiB);

    tsplit_kernel<<<dim3(1024 / 32, 3072 / 32), 256, 0, stream>>>(Wqkv, WtQh, WtQl, 1024, 3072);

    // QKV: Q|K split into Xh/Xl (stride 2048), V transposed hi-only into Vth
    gemm2<0, 0, 1, 1><<<dim3(3072 / 128, MTOT / 128), 256, 0, stream>>>(
        seq, nullptr, nullptr, WtQh, WtQl, nullptr,
        nullptr, Xh, Xl, Vth, MTOT, 3072, 1024, 2048);

    attn_mfma3<<<dim3(BSZ * NHEAD, SEQ / 128), 256, 0, stream>>>(Xh, Xl, Vth, mask, atth, attl);

    tsplit_kernel<<<dim3(1024 / 32, 2048 / 32), 256, 0, stream>>>(W1, Wt1h, Wt1l, 1024, 2048);
    tsplit_kernel<<<dim3(2048 / 32, 1024 / 32), 256, 0, stream>>>(W2, Wt2h, Wt2l, 2048, 1024);

    gemm2<1, 1, 1, 0><<<dim3(2048 / 128, MTOT / 128), 256, 0, stream>>>(
        nullptr, atth, attl, Wt1h, Wt1l, b1,
        nullptr, hidh, hidl, nullptr, MTOT, 2048, 1024, 2048);

    gemm2<1, 0, 0, 0><<<dim3(1024 / 128, MTOT / 128), 256, 0, stream>>>(
        nullptr, hidh, hidl, Wt2h, Wt2l, b2,
        out, nullptr, nullptr, nullptr, MTOT, 1024, 2048, 1024);
}

// Round 6
// 397.701 us; speedup vs baseline: 4.0279x; 1.0281x over previous
//
#include <hip/hip_runtime.h>
#include <math.h>

#define SEQ   2048
#define NHEAD 16
#define HD    64
#define BSZ   2
#define MTOT  (BSZ*SEQ)   // 4096

typedef __bf16 bf16x8 __attribute__((ext_vector_type(8)));
typedef short  s16x8  __attribute__((ext_vector_type(8)));
typedef short  s16x4  __attribute__((ext_vector_type(4)));
typedef float  f32x4  __attribute__((ext_vector_type(4)));

// round-to-nearest-even fp32 -> bf16 (raw short)
__device__ __forceinline__ short f2bf(float x) {
    unsigned u = __builtin_bit_cast(unsigned, x);
    u = (u + 0x7fffu + ((u >> 16) & 1u)) >> 16;
    return (short)u;
}
__device__ __forceinline__ float bf2f(short h) {
    unsigned u = ((unsigned)(unsigned short)h) << 16;
    return __builtin_bit_cast(float, u);
}

// async global->LDS 16B: dest = wave-uniform lds base + lane*16
__device__ __forceinline__ void gl_lds16(const short* g, short* l) {
    __builtin_amdgcn_global_load_lds(
        (const __attribute__((address_space(1))) unsigned int*)g,
        (__attribute__((address_space(3))) unsigned int*)l, 16, 0, 0);
}

// ---------------------------------------------------------------------------
// Transpose+split one 32x32 tile: W[K,N] fp32 -> Th/Tl [N,K] bf16 hi/lo
// ---------------------------------------------------------------------------
__device__ __forceinline__ void tsplit_tile(const float* __restrict__ W,
    short* __restrict__ Th, short* __restrict__ Tl,
    int K, int N, int k0, int n0, float (*T)[33], int t)
{
    {
        const int kl = t >> 3;
        const int nl = (t & 7) * 4;
        const float4 v = *(const float4*)&W[(size_t)(k0 + kl) * N + n0 + nl];
        T[nl + 0][kl] = v.x; T[nl + 1][kl] = v.y;
        T[nl + 2][kl] = v.z; T[nl + 3][kl] = v.w;
    }
    __syncthreads();
    {
        const int nl = t >> 3;
        const int kl = (t & 7) * 4;
        s16x4 h, l;
        #pragma unroll
        for (int c = 0; c < 4; ++c) {
            const float x = T[nl][kl + c];
            const short hb = f2bf(x);
            h[c] = hb;
            l[c] = f2bf(x - bf2f(hb));
        }
        const size_t o = (size_t)(n0 + nl) * K + k0 + kl;
        *(s16x4*)&Th[o] = h;
        *(s16x4*)&Tl[o] = l;
    }
}

// ---------------------------------------------------------------------------
// prep: blocks [0,1024) seq split -> seqh/seql (d_out scratch);
//       [1024,4096) Wqkv tsplit; [4096,6144) W1 tsplit.
// ---------------------------------------------------------------------------
__global__ __launch_bounds__(256)
void prep_kernel(const float* __restrict__ seq, short* __restrict__ seqh, short* __restrict__ seql,
                 const float* __restrict__ Wqkv, short* __restrict__ WtQh, short* __restrict__ WtQl,
                 const float* __restrict__ W1, short* __restrict__ Wt1h, short* __restrict__ Wt1l)
{
    __shared__ float T[32][33];
    const int t = threadIdx.x;
    const int bid = blockIdx.x;
    if (bid < 1024) {
        const size_t base = (size_t)bid * 4096 + (size_t)t * 16;
        #pragma unroll
        for (int c = 0; c < 4; ++c) {
            const float4 v = *(const float4*)&seq[base + c * 4];
            const float xs[4] = {v.x, v.y, v.z, v.w};
            s16x4 h, l;
            #pragma unroll
            for (int e = 0; e < 4; ++e) {
                const short hb = f2bf(xs[e]);
                h[e] = hb;
                l[e] = f2bf(xs[e] - bf2f(hb));
            }
            *(s16x4*)&seqh[base + c * 4] = h;
            *(s16x4*)&seql[base + c * 4] = l;
        }
    } else if (bid < 4096) {
        const int idx = bid - 1024;
        tsplit_tile(Wqkv, WtQh, WtQl, 1024, 3072, (idx & 31) * 32, (idx >> 5) * 32, T, t);
    } else {
        const int idx = bid - 4096;
        tsplit_tile(W1, Wt1h, Wt1l, 1024, 2048, (idx & 31) * 32, (idx >> 5) * 32, T, t);
    }
}

// ---------------------------------------------------------------------------
// util: blocks [0,4096) transpose Vnat[4096][1024] -> Vth[1024][4096];
//       [4096,6144) W2 tsplit.
// ---------------------------------------------------------------------------
__global__ __launch_bounds__(256)
void util_kernel(const short* __restrict__ Vnat, short* __restrict__ Vth,
                 const float* __restrict__ W2, short* __restrict__ Wt2h, short* __restrict__ Wt2l)
{
    __shared__ float T[32][33];
    const int t = threadIdx.x;
    const int bid = blockIdx.x;
    if (bid < 4096) {
        short (*TT)[36] = (short(*)[36])T;   // 32x36 shorts fits in T
        const int r0 = (bid & 127) * 32;     // token tile
        const int f0 = (bid >> 7) * 32;      // feature tile
        {
            const int rl = t >> 3;
            const int fl = (t & 7) * 4;
            const s16x4 v = *(const s16x4*)&Vnat[(size_t)(r0 + rl) * 1024 + f0 + fl];
            TT[fl + 0][rl] = v[0]; TT[fl + 1][rl] = v[1];
            TT[fl + 2][rl] = v[2]; TT[fl + 3][rl] = v[3];
        }
        __syncthreads();
        {
            const int fl = t >> 3;
            const int rl = (t & 7) * 4;
            s16x4 o;
            o[0] = TT[fl][rl + 0]; o[1] = TT[fl][rl + 1];
            o[2] = TT[fl][rl + 2]; o[3] = TT[fl][rl + 3];
            *(s16x4*)&Vth[(size_t)(f0 + fl) * 4096 + r0 + rl] = o;
        }
    } else {
        const int idx = bid - 4096;
        tsplit_tile(W2, Wt2h, Wt2l, 2048, 1024, (idx & 63) * 32, (idx >> 6) * 32, T, t);
    }
}

// ---------------------------------------------------------------------------
// bf16x3 split MFMA GEMM v3: all operands pre-split, global_load_lds staging.
// Block 128 x NB (NB=128 or 64), BK=32, 4 waves.
// VT=1 (QKV): cols>=2048 -> Vnat bf16 [row][col-2048] natural store.
// ---------------------------------------------------------------------------
template<int ACT, int OSPLIT, int VT, int NB>
__global__ __launch_bounds__(256, 2)
void gemm2(const short* __restrict__ Ahg, const short* __restrict__ Alg,
           const short* __restrict__ Bhg, const short* __restrict__ Blg,
           const float* __restrict__ bias,
           float* __restrict__ Cf, short* __restrict__ Chg, short* __restrict__ Clg,
           short* __restrict__ Vng,
           int M, int N, int K, int NOUT)
{
    constexpr int NJ = NB / 32;
    __shared__ short AhL[128 * 32];
    __shared__ short AlL[128 * 32];
    __shared__ short BhL[NB * 32];
    __shared__ short BlL[NB * 32];

    const int t    = threadIdx.x;
    const int m0   = blockIdx.y * 128;
    const int n0   = blockIdx.x * NB;
    const int wave = t >> 6;
    const int lane = t & 63;
    const int r    = lane & 15;
    const int qd   = lane >> 4;
    const int wm   = (wave & 1) * 64;
    const int wn   = (wave >> 1) * (NB / 2);

    f32x4 acc[4][NJ];
    #pragma unroll
    for (int i = 0; i < 4; ++i)
        #pragma unroll
        for (int j = 0; j < NJ; ++j) acc[i][j] = (f32x4){0.f, 0.f, 0.f, 0.f};

    for (int k0 = 0; k0 < K; k0 += 32) {
        __syncthreads();
        #pragma unroll
        for (int s = 0; s < 2; ++s) {
            const int p    = wave * 2 + s;
            const int srow = p * 16 + (lane >> 2);
            const int sg   = (lane & 3) ^ ((srow >> 1) & 3);
            const size_t ga = (size_t)(m0 + srow) * K + k0 + sg * 8;
            gl_lds16(&Ahg[ga], &AhL[p * 512]);
            gl_lds16(&Alg[ga], &AlL[p * 512]);
        }
        #pragma unroll
        for (int s = 0; s < NB / 64; ++s) {
            const int p    = wave * (NB / 64) + s;
            const int srow = p * 16 + (lane >> 2);
            const int sg   = (lane & 3) ^ ((srow >> 1) & 3);
            const size_t gb = (size_t)(n0 + srow) * K + k0 + sg * 8;
            gl_lds16(&Bhg[gb], &BhL[p * 512]);
            gl_lds16(&Blg[gb], &BlL[p * 512]);
        }
        __syncthreads();

        bf16x8 afh[4], afl[4], bfh[NJ], bfl[NJ];
        #pragma unroll
        for (int i = 0; i < 4; ++i) {
            const int row = wm + i * 16 + r;
            const int oa = row * 32 + ((qd ^ ((row >> 1) & 3)) * 8);
            afh[i] = __builtin_bit_cast(bf16x8, *(const s16x8*)&AhL[oa]);
            afl[i] = __builtin_bit_cast(bf16x8, *(const s16x8*)&AlL[oa]);
        }
        #pragma unroll
        for (int j = 0; j < NJ; ++j) {
            const int row = wn + j * 16 + r;
            const int ob = row * 32 + ((qd ^ ((row >> 1) & 3)) * 8);
            bfh[j] = __builtin_bit_cast(bf16x8, *(const s16x8*)&BhL[ob]);
            bfl[j] = __builtin_bit_cast(bf16x8, *(const s16x8*)&BlL[ob]);
        }

        #pragma unroll
        for (int i = 0; i < 4; ++i)
            #pragma unroll
            for (int j = 0; j < NJ; ++j) {
                acc[i][j] = __builtin_amdgcn_mfma_f32_16x16x32_bf16(afh[i], bfh[j], acc[i][j], 0, 0, 0);
                acc[i][j] = __builtin_amdgcn_mfma_f32_16x16x32_bf16(afh[i], bfl[j], acc[i][j], 0, 0, 0);
                acc[i][j] = __builtin_amdgcn_mfma_f32_16x16x32_bf16(afl[i], bfh[j], acc[i][j], 0, 0, 0);
            }
    }

    // epilogue: C/D layout col=lane&15, row=quad*4+g
    #pragma unroll
    for (int i = 0; i < 4; ++i)
        #pragma unroll
        for (int j = 0; j < NJ; ++j) {
            const int col = n0 + wn + j * 16 + r;
            if (VT && col >= 2048) {
                #pragma unroll
                for (int g = 0; g < 4; ++g) {
                    const int row = m0 + wm + i * 16 + qd * 4 + g;
                    Vng[(size_t)row * 1024 + (col - 2048)] = f2bf(acc[i][j][g]);
                }
            } else {
                const float bv = bias ? bias[col] : 0.f;
                #pragma unroll
                for (int g = 0; g < 4; ++g) {
                    const int row = m0 + wm + i * 16 + qd * 4 + g;
                    float x = acc[i][j][g] + bv;
                    if (ACT == 1) x = x / (1.0f + __expf(-x));
                    if (OSPLIT) {
                        const short hb = f2bf(x);
                        Chg[(size_t)row * NOUT + col] = hb;
                        Clg[(size_t)row * NOUT + col] = f2bf(x - bf2f(hb));
                    } else {
                        Cf[(size_t)row * NOUT + col] = x;
                    }
                }
            }
        }
}

// ---------------------------------------------------------------------------
// MFMA flash attention v3 (round-5 proven, unchanged).
// Xh/Xl [4096][2048] = Q|K presplit; Vth [1024][4096] = V^T bf16.
// Fixed-offset softmax p = exp(s-16); row-sum via mfma(P, ones).
// K/V double-buffered global_load_lds, one barrier per tile.
// ---------------------------------------------------------------------------
__global__ __launch_bounds__(256, 2)
void attn_mfma3(const short* __restrict__ Xh, const short* __restrict__ Xl,
                const short* __restrict__ Vth, const float* __restrict__ mask,
                short* __restrict__ atth, short* __restrict__ attl)
{
    __shared__ short KhL[2 * 64 * 64];
    __shared__ short KlL[2 * 64 * 64];
    __shared__ short VhL[2 * 64 * 64];
    __shared__ short PhL[128 * 64];

    const int t    = threadIdx.x;
    const int lane = t & 63;
    const int w    = t >> 6;
    const int r    = lane & 15;
    const int qd   = lane >> 4;
    const int b    = blockIdx.x >> 4;
    const int h    = blockIdx.x & 15;
    const int q0   = blockIdx.y * 128;

    const int srow0 = (lane >> 3);
    const int sgx   = lane & 7;

    bf16x8 qh[2][2], ql[2][2];
    #pragma unroll
    for (int i = 0; i < 2; ++i) {
        const size_t qoff = (size_t)(b * SEQ + q0 + w * 32 + i * 16 + r) * 2048 + h * 64;
        #pragma unroll
        for (int ks = 0; ks < 2; ++ks) {
            qh[i][ks] = __builtin_bit_cast(bf16x8, *(const s16x8*)&Xh[qoff + ks * 32 + qd * 8]);
            ql[i][ks] = __builtin_bit_cast(bf16x8, *(const s16x8*)&Xl[qoff + ks * 32 + qd * 8]);
        }
    }

    s16x8 ones_s;
    #pragma unroll
    for (int c = 0; c < 8; ++c) ones_s[c] = (short)0x3F80;
    const bf16x8 ones = __builtin_bit_cast(bf16x8, ones_s);

    f32x4 O[2][4], Lac[2];
    #pragma unroll
    for (int i = 0; i < 2; ++i) {
        Lac[i] = (f32x4){0.f, 0.f, 0.f, 0.f};
        #pragma unroll
        for (int j = 0; j < 4; ++j) O[i][j] = (f32x4){0.f, 0.f, 0.f, 0.f};
    }

    auto stage = [&](int kt, int buf) {
        const int k0   = kt * 64;
        const int tok0 = b * SEQ + k0;
        const int bo   = buf * 4096;
        #pragma unroll
        for (int s = 0; s < 2; ++s) {
            const int p    = w * 2 + s;
            const int srow = p * 8 + srow0;
            const int sg   = sgx ^ (srow & 7);
            const size_t gk = (size_t)(tok0 + srow) * 2048 + 1024 + h * 64 + sg * 8;
            gl_lds16(&Xh[gk], &KhL[bo + p * 512]);
            gl_lds16(&Xl[gk], &KlL[bo + p * 512]);
            const size_t gv = (size_t)(h * 64 + srow) * 4096 + (size_t)b * SEQ + k0 + sg * 8;
            gl_lds16(&Vth[gv], &VhL[bo + p * 512]);
        }
    };

    stage(0, 0);

    for (int kt = 0; kt < SEQ / 64; ++kt) {
        const int cur = kt & 1;
        const int k0  = kt * 64;

        __syncthreads();
        if (kt + 1 < SEQ / 64) stage(kt + 1, 1 - cur);

        float mreg[2][4][4];
        #pragma unroll
        for (int i = 0; i < 2; ++i)
            #pragma unroll
            for (int g = 0; g < 4; ++g) {
                const size_t mrow = (size_t)(q0 + w * 32 + i * 16 + qd * 4 + g) * SEQ + k0;
                #pragma unroll
                for (int j = 0; j < 4; ++j)
                    mreg[i][g][j] = mask[mrow + j * 16 + r];
            }

        const int co = cur * 4096;
        f32x4 S[2][4];
        #pragma unroll
        for (int i = 0; i < 2; ++i)
            #pragma unroll
            for (int j = 0; j < 4; ++j) S[i][j] = (f32x4){0.f, 0.f, 0.f, 0.f};
        #pragma unroll
        for (int ks = 0; ks < 2; ++ks) {
            bf16x8 kfh[4], kfl[4];
            #pragma unroll
            for (int j = 0; j < 4; ++j) {
                const int row = j * 16 + r;
                const int off = co + row * 64 + (((ks * 4 + qd) ^ (row & 7)) * 8);
                kfh[j] = __builtin_bit_cast(bf16x8, *(const s16x8*)&KhL[off]);
                kfl[j] = __builtin_bit_cast(bf16x8, *(const s16x8*)&KlL[off]);
            }
            #pragma unroll
            for (int i = 0; i < 2; ++i)
                #pragma unroll
                for (int j = 0; j < 4; ++j) {
                    S[i][j] = __builtin_amdgcn_mfma_f32_16x16x32_bf16(qh[i][ks], kfh[j], S[i][j], 0, 0, 0);
                    S[i][j] = __builtin_amdgcn_mfma_f32_16x16x32_bf16(qh[i][ks], kfl[j], S[i][j], 0, 0, 0);
                    S[i][j] = __builtin_amdgcn_mfma_f32_16x16x32_bf16(ql[i][ks], kfh[j], S[i][j], 0, 0, 0);
                }
        }

        #pragma unroll
        for (int i = 0; i < 2; ++i)
            #pragma unroll
            for (int j = 0; j < 4; ++j)
                #pragma unroll
                for (int g = 0; g < 4; ++g)
                    S[i][j][g] = __expf(fmaf(S[i][j][g], 0.125f, mreg[i][g][j]) - 16.0f);

        #pragma unroll
        for (int i = 0; i < 2; ++i)
            #pragma unroll
            for (int j = 0; j < 4; ++j)
                #pragma unroll
                for (int g = 0; g < 4; ++g) {
                    const int prow = w * 32 + i * 16 + qd * 4 + g;
                    const int gr   = (j * 2 + (r >> 3)) ^ ((prow >> 1) & 7);
                    PhL[prow * 64 + gr * 8 + (r & 7)] = f2bf(S[i][j][g]);
                }

        #pragma unroll
        for (int ks = 0; ks < 2; ++ks) {
            bf16x8 pfh[2], vfh[4];
            #pragma unroll
            for (int i = 0; i < 2; ++i) {
                const int row = w * 32 + i * 16 + r;
                pfh[i] = __builtin_bit_cast(bf16x8,
                    *(const s16x8*)&PhL[row * 64 + (((ks * 4 + qd) ^ ((row >> 1) & 7)) * 8)]);
            }
            #pragma unroll
            for (int j = 0; j < 4; ++j) {
                const int row = j * 16 + r;
                vfh[j] = __builtin_bit_cast(bf16x8,
                    *(const s16x8*)&VhL[co + row * 64 + (((ks * 4 + qd) ^ (row & 7)) * 8)]);
            }
            #pragma unroll
            for (int i = 0; i < 2; ++i) {
                Lac[i] = __builtin_amdgcn_mfma_f32_16x16x32_bf16(pfh[i], ones, Lac[i], 0, 0, 0);
                #pragma unroll
                for (int j = 0; j < 4; ++j)
                    O[i][j] = __builtin_amdgcn_mfma_f32_16x16x32_bf16(pfh[i], vfh[j], O[i][j], 0, 0, 0);
            }
        }
    }

    #pragma unroll
    for (int i = 0; i < 2; ++i)
        #pragma unroll
        for (int g = 0; g < 4; ++g) {
            const float inv = 1.0f / Lac[i][g];
            const size_t row = (size_t)(b * SEQ + q0 + w * 32 + i * 16 + qd * 4 + g);
            #pragma unroll
            for (int j = 0; j < 4; ++j) {
                const float x = O[i][j][g] * inv;
                const short hb = f2bf(x);
                const size_t o = row * 1024 + h * 64 + j * 16 + r;
                atth[o] = hb;
                attl[o] = f2bf(x - bf2f(hb));
            }
        }
}

// ---------------------------------------------------------------------------
extern "C" void kernel_launch(void* const* d_in, const int* in_sizes, int n_in,
                              void* d_out, int out_size, void* d_ws, size_t ws_size,
                              hipStream_t stream)
{
    const float* seq  = (const float*)d_in[0];
    const float* mask = (const float*)d_in[1];
    const float* Wqkv = (const float*)d_in[2];
    const float* W1   = (const float*)d_in[3];
    const float* b1   = (const float*)d_in[4];
    const float* W2   = (const float*)d_in[5];
    const float* b2   = (const float*)d_in[6];
    float* out = (float*)d_out;

    // ws (64 MiB) timeline:
    //  P0 prep : WtQ [48,60), Wt1 [40,48); seq-split -> d_out [0,16)
    //  P1 QKV  : Xh [0,16), Xl [16,32), Vnat [32,40)
    //  P2 util : Vth [48,56) (WtQ dead), Wt2 [56,64)
    //  P3 attn : atth -> d_out [0,8), attl -> d_out [8,16)  (seq-split dead)
    //  P4 FFN1 : hidh [0,16), hidl [16,32)  (X, Vnat dead)
    //  P5 FFN2 : out -> d_out (att consumed)
    const size_t MiB = 1048576;
    char* B = (char*)d_ws;
    short* Xh   = (short*)(B + 0);
    short* Xl   = (short*)(B + 16 * MiB);
    short* Vnat = (short*)(B + 32 * MiB);
    short* Wt1h = (short*)(B + 40 * MiB);
    short* Wt1l = (short*)(B + 44 * MiB);
    short* WtQh = (short*)(B + 48 * MiB);
    short* WtQl = (short*)(B + 54 * MiB);
    short* Vth  = (short*)(B + 48 * MiB);
    short* Wt2h = (short*)(B + 56 * MiB);
    short* Wt2l = (short*)(B + 60 * MiB);
    short* hidh = (short*)(B + 0);
    short* hidl = (short*)(B + 16 * MiB);

    short* seqh = (short*)d_out;
    short* seql = seqh + (size_t)MTOT * 1024;
    short* atth = (short*)d_out;
    short* attl = atth + (size_t)MTOT * 1024;

    // P0: seq split + Wqkv/W1 transpose-splits (one launch)
    prep_kernel<<<6144, 256, 0, stream>>>(seq, seqh, seql, Wqkv, WtQh, WtQl, W1, Wt1h, Wt1l);

    // P1: QKV GEMM — Q|K split -> Xh/Xl (stride 2048), V natural bf16 -> Vnat
    gemm2<0, 1, 1, 128><<<dim3(3072 / 128, MTOT / 128), 256, 0, stream>>>(
        seqh, seql, WtQh, WtQl, nullptr,
        nullptr, Xh, Xl, Vnat, MTOT, 3072, 1024, 2048);

    // P2: V transpose + W2 split (one launch)
    util_kernel<<<6144, 256, 0, stream>>>(Vnat, Vth, W2, Wt2h, Wt2l);

    // P3: flash attention -> att hi/lo in d_out
    attn_mfma3<<<dim3(BSZ * NHEAD, SEQ / 128), 256, 0, stream>>>(Xh, Xl, Vth, mask, atth, attl);

    // P4: FFN1 + SiLU -> hid hi/lo
    gemm2<1, 1, 0, 128><<<dim3(2048 / 128, MTOT / 128), 256, 0, stream>>>(
        atth, attl, Wt1h, Wt1l, b1,
        nullptr, hidh, hidl, nullptr, MTOT, 2048, 1024, 2048);

    // P5: FFN2 + bias -> out (BN=64: 512 blocks = 2/CU)
    gemm2<0, 0, 0, 64><<<dim3(1024 / 64, MTOT / 128), 256, 0, stream>>>(
        hidh, hidl, Wt2h, Wt2l, b2,
        out, nullptr, nullptr, nullptr, MTOT, 1024, 2048, 1024);
}

// Round 8
// 356.388 us; speedup vs baseline: 4.4948x; 1.1159x over previous
//
#include <hip/hip_runtime.h>
#include <math.h>

#define SEQ   2048
#define NHEAD 16
#define HD    64
#define BSZ   2
#define MTOT  (BSZ*SEQ)   // 4096

#define LOG2E    1.4426950408889634f
#define C_SCALE  0.18033688011112043f    // 0.125 * log2(e)
#define C_MOFF  -23.083120654223414f     // -16 * log2(e)

typedef __bf16 bf16x8 __attribute__((ext_vector_type(8)));
typedef short  s16x8  __attribute__((ext_vector_type(8)));
typedef short  s16x4  __attribute__((ext_vector_type(4)));
typedef float  f32x4  __attribute__((ext_vector_type(4)));

// round-to-nearest-even fp32 -> bf16 (raw short)
__device__ __forceinline__ short f2bf(float x) {
    unsigned u = __builtin_bit_cast(unsigned, x);
    u = (u + 0x7fffu + ((u >> 16) & 1u)) >> 16;
    return (short)u;
}
__device__ __forceinline__ float bf2f(short h) {
    unsigned u = ((unsigned)(unsigned short)h) << 16;
    return __builtin_bit_cast(float, u);
}

// async global->LDS 16B: dest = wave-uniform lds base + lane*16
__device__ __forceinline__ void gl_lds16(const short* g, short* l) {
    __builtin_amdgcn_global_load_lds(
        (const __attribute__((address_space(1))) unsigned int*)g,
        (__attribute__((address_space(3))) unsigned int*)l, 16, 0, 0);
}

// ---------------------------------------------------------------------------
// Transpose+split one 32x32 tile: W[K,N] fp32 -> Th/Tl [N,K] bf16 hi/lo
// ---------------------------------------------------------------------------
__device__ __forceinline__ void tsplit_tile(const float* __restrict__ W,
    short* __restrict__ Th, short* __restrict__ Tl,
    int K, int N, int k0, int n0, float (*T)[33], int t)
{
    {
        const int kl = t >> 3;
        const int nl = (t & 7) * 4;
        const float4 v = *(const float4*)&W[(size_t)(k0 + kl) * N + n0 + nl];
        T[nl + 0][kl] = v.x; T[nl + 1][kl] = v.y;
        T[nl + 2][kl] = v.z; T[nl + 3][kl] = v.w;
    }
    __syncthreads();
    {
        const int nl = t >> 3;
        const int kl = (t & 7) * 4;
        s16x4 h, l;
        #pragma unroll
        for (int c = 0; c < 4; ++c) {
            const float x = T[nl][kl + c];
            const short hb = f2bf(x);
            h[c] = hb;
            l[c] = f2bf(x - bf2f(hb));
        }
        const size_t o = (size_t)(n0 + nl) * K + k0 + kl;
        *(s16x4*)&Th[o] = h;
        *(s16x4*)&Tl[o] = l;
    }
}

// ---------------------------------------------------------------------------
// prep: [0,1024) seq -> seqh (bf16 hi only);
//       [1024,4096) Wqkv tsplit; [4096,6144) W1 tsplit.
// ---------------------------------------------------------------------------
__global__ __launch_bounds__(256)
void prep_kernel(const float* __restrict__ seq, short* __restrict__ seqh,
                 const float* __restrict__ Wqkv, short* __restrict__ WtQh, short* __restrict__ WtQl,
                 const float* __restrict__ W1, short* __restrict__ Wt1h, short* __restrict__ Wt1l)
{
    __shared__ float T[32][33];
    const int t = threadIdx.x;
    const int bid = blockIdx.x;
    if (bid < 1024) {
        const size_t base = (size_t)bid * 4096 + (size_t)t * 16;
        #pragma unroll
        for (int c = 0; c < 4; ++c) {
            const float4 v = *(const float4*)&seq[base + c * 4];
            s16x4 h;
            h[0] = f2bf(v.x); h[1] = f2bf(v.y); h[2] = f2bf(v.z); h[3] = f2bf(v.w);
            *(s16x4*)&seqh[base + c * 4] = h;
        }
    } else if (bid < 4096) {
        const int idx = bid - 1024;
        tsplit_tile(Wqkv, WtQh, WtQl, 1024, 3072, (idx & 31) * 32, (idx >> 5) * 32, T, t);
    } else {
        const int idx = bid - 4096;
        tsplit_tile(W1, Wt1h, Wt1l, 1024, 2048, (idx & 31) * 32, (idx >> 5) * 32, T, t);
    }
}

// ---------------------------------------------------------------------------
// util: [0,4096) transpose Vnat[4096][1024] -> Vth[1024][4096]; [4096,6144) W2 tsplit.
// ---------------------------------------------------------------------------
__global__ __launch_bounds__(256)
void util_kernel(const short* __restrict__ Vnat, short* __restrict__ Vth,
                 const float* __restrict__ W2, short* __restrict__ Wt2h, short* __restrict__ Wt2l)
{
    __shared__ float T[32][33];
    const int t = threadIdx.x;
    const int bid = blockIdx.x;
    if (bid < 4096) {
        short (*TT)[36] = (short(*)[36])T;
        const int r0 = (bid & 127) * 32;
        const int f0 = (bid >> 7) * 32;
        {
            const int rl = t >> 3;
            const int fl = (t & 7) * 4;
            const s16x4 v = *(const s16x4*)&Vnat[(size_t)(r0 + rl) * 1024 + f0 + fl];
            TT[fl + 0][rl] = v[0]; TT[fl + 1][rl] = v[1];
            TT[fl + 2][rl] = v[2]; TT[fl + 3][rl] = v[3];
        }
        __syncthreads();
        {
            const int fl = t >> 3;
            const int rl = (t & 7) * 4;
            s16x4 o;
            o[0] = TT[fl][rl + 0]; o[1] = TT[fl][rl + 1];
            o[2] = TT[fl][rl + 2]; o[3] = TT[fl][rl + 3];
            *(s16x4*)&Vth[(size_t)(f0 + fl) * 4096 + r0 + rl] = o;
        }
    } else {
        const int idx = bid - 4096;
        tsplit_tile(W2, Wt2h, Wt2l, 2048, 1024, (idx & 63) * 32, (idx >> 6) * 32, T, t);
    }
}

// ---------------------------------------------------------------------------
// split MFMA GEMM v4. A single bf16 (2-term: Ah*Bh + Ah*Bl), B hi/lo.
// OMODE: 0 fp32 out, 1 split hi/lo out, 2 hi-only out. ACT 1: SiLU.
// VT=1 (QKV): cols>=2048 -> Vnat bf16 natural store.
// Block 128 x NB, BK=32, 4 waves, global_load_lds staging, XOR swizzle.
// ---------------------------------------------------------------------------
template<int ACT, int OMODE, int VT, int NB>
__global__ __launch_bounds__(256, 2)
void gemm2(const short* __restrict__ Ahg,
           const short* __restrict__ Bhg, const short* __restrict__ Blg,
           const float* __restrict__ bias,
           float* __restrict__ Cf, short* __restrict__ Chg, short* __restrict__ Clg,
           short* __restrict__ Vng,
           int M, int N, int K, int NOUT)
{
    constexpr int NJ = NB / 32;
    __shared__ short AhL[128 * 32];
    __shared__ short BhL[NB * 32];
    __shared__ short BlL[NB * 32];

    const int t    = threadIdx.x;
    const int m0   = blockIdx.y * 128;
    const int n0   = blockIdx.x * NB;
    const int wave = t >> 6;
    const int lane = t & 63;
    const int r    = lane & 15;
    const int qd   = lane >> 4;
    const int wm   = (wave & 1) * 64;
    const int wn   = (wave >> 1) * (NB / 2);

    f32x4 acc[4][NJ];
    #pragma unroll
    for (int i = 0; i < 4; ++i)
        #pragma unroll
        for (int j = 0; j < NJ; ++j) acc[i][j] = (f32x4){0.f, 0.f, 0.f, 0.f};

    for (int k0 = 0; k0 < K; k0 += 32) {
        __syncthreads();
        #pragma unroll
        for (int s = 0; s < 2; ++s) {
            const int p    = wave * 2 + s;
            const int srow = p * 16 + (lane >> 2);
            const int sg   = (lane & 3) ^ ((srow >> 1) & 3);
            const size_t ga = (size_t)(m0 + srow) * K + k0 + sg * 8;
            gl_lds16(&Ahg[ga], &AhL[p * 512]);
        }
        #pragma unroll
        for (int s = 0; s < NB / 64; ++s) {
            const int p    = wave * (NB / 64) + s;
            const int srow = p * 16 + (lane >> 2);
            const int sg   = (lane & 3) ^ ((srow >> 1) & 3);
            const size_t gb = (size_t)(n0 + srow) * K + k0 + sg * 8;
            gl_lds16(&Bhg[gb], &BhL[p * 512]);
            gl_lds16(&Blg[gb], &BlL[p * 512]);
        }
        __syncthreads();

        bf16x8 afh[4], bfh[NJ], bfl[NJ];
        #pragma unroll
        for (int i = 0; i < 4; ++i) {
            const int row = wm + i * 16 + r;
            const int oa = row * 32 + ((qd ^ ((row >> 1) & 3)) * 8);
            afh[i] = __builtin_bit_cast(bf16x8, *(const s16x8*)&AhL[oa]);
        }
        #pragma unroll
        for (int j = 0; j < NJ; ++j) {
            const int row = wn + j * 16 + r;
            const int ob = row * 32 + ((qd ^ ((row >> 1) & 3)) * 8);
            bfh[j] = __builtin_bit_cast(bf16x8, *(const s16x8*)&BhL[ob]);
            bfl[j] = __builtin_bit_cast(bf16x8, *(const s16x8*)&BlL[ob]);
        }

        #pragma unroll
        for (int i = 0; i < 4; ++i)
            #pragma unroll
            for (int j = 0; j < NJ; ++j) {
                acc[i][j] = __builtin_amdgcn_mfma_f32_16x16x32_bf16(afh[i], bfh[j], acc[i][j], 0, 0, 0);
                acc[i][j] = __builtin_amdgcn_mfma_f32_16x16x32_bf16(afh[i], bfl[j], acc[i][j], 0, 0, 0);
            }
    }

    // epilogue: C/D layout col=lane&15, row=quad*4+g
    #pragma unroll
    for (int i = 0; i < 4; ++i)
        #pragma unroll
        for (int j = 0; j < NJ; ++j) {
            const int col = n0 + wn + j * 16 + r;
            if (VT && col >= 2048) {
                #pragma unroll
                for (int g = 0; g < 4; ++g) {
                    const int row = m0 + wm + i * 16 + qd * 4 + g;
                    Vng[(size_t)row * 1024 + (col - 2048)] = f2bf(acc[i][j][g]);
                }
            } else {
                const float bv = bias ? bias[col] : 0.f;
                #pragma unroll
                for (int g = 0; g < 4; ++g) {
                    const int row = m0 + wm + i * 16 + qd * 4 + g;
                    float x = acc[i][j][g] + bv;
                    if (ACT == 1) x = x / (1.0f + __expf(-x));
                    if (OMODE == 0) {
                        Cf[(size_t)row * NOUT + col] = x;
                    } else if (OMODE == 1) {
                        const short hb = f2bf(x);
                        Chg[(size_t)row * NOUT + col] = hb;
                        Clg[(size_t)row * NOUT + col] = f2bf(x - bf2f(hb));
                    } else {
                        Chg[(size_t)row * NOUT + col] = f2bf(x);
                    }
                }
            }
        }
}

// ---------------------------------------------------------------------------
// MFMA flash attention v4: round-5 structure; mask rescale folded into the
// (MFMA-overlapped) mask load; exp2 softmax; output hi-only.
// ---------------------------------------------------------------------------
__global__ __launch_bounds__(256, 2)
void attn_mfma3(const short* __restrict__ Xh, const short* __restrict__ Xl,
                const short* __restrict__ Vth, const float* __restrict__ mask,
                short* __restrict__ atth)
{
    __shared__ short KhL[2 * 64 * 64];
    __shared__ short KlL[2 * 64 * 64];
    __shared__ short VhL[2 * 64 * 64];
    __shared__ short PhL[128 * 64];

    const int t    = threadIdx.x;
    const int lane = t & 63;
    const int w    = t >> 6;
    const int r    = lane & 15;
    const int qd   = lane >> 4;
    const int b    = blockIdx.x >> 4;
    const int h    = blockIdx.x & 15;
    const int q0   = blockIdx.y * 128;

    const int srow0 = (lane >> 3);
    const int sgx   = lane & 7;

    bf16x8 qh[2][2], ql[2][2];
    #pragma unroll
    for (int i = 0; i < 2; ++i) {
        const size_t qoff = (size_t)(b * SEQ + q0 + w * 32 + i * 16 + r) * 2048 + h * 64;
        #pragma unroll
        for (int ks = 0; ks < 2; ++ks) {
            qh[i][ks] = __builtin_bit_cast(bf16x8, *(const s16x8*)&Xh[qoff + ks * 32 + qd * 8]);
            ql[i][ks] = __builtin_bit_cast(bf16x8, *(const s16x8*)&Xl[qoff + ks * 32 + qd * 8]);
        }
    }

    s16x8 ones_s;
    #pragma unroll
    for (int c = 0; c < 8; ++c) ones_s[c] = (short)0x3F80;
    const bf16x8 ones = __builtin_bit_cast(bf16x8, ones_s);

    f32x4 O[2][4], Lac[2];
    #pragma unroll
    for (int i = 0; i < 2; ++i) {
        Lac[i] = (f32x4){0.f, 0.f, 0.f, 0.f};
        #pragma unroll
        for (int j = 0; j < 4; ++j) O[i][j] = (f32x4){0.f, 0.f, 0.f, 0.f};
    }

    auto stage = [&](int kt, int buf) {
        const int k0   = kt * 64;
        const int tok0 = b * SEQ + k0;
        const int bo   = buf * 4096;
        #pragma unroll
        for (int s = 0; s < 2; ++s) {
            const int p    = w * 2 + s;
            const int srow = p * 8 + srow0;
            const int sg   = sgx ^ (srow & 7);
            const size_t gk = (size_t)(tok0 + srow) * 2048 + 1024 + h * 64 + sg * 8;
            gl_lds16(&Xh[gk], &KhL[bo + p * 512]);
            gl_lds16(&Xl[gk], &KlL[bo + p * 512]);
            const size_t gv = (size_t)(h * 64 + srow) * 4096 + (size_t)b * SEQ + k0 + sg * 8;
            gl_lds16(&Vth[gv], &VhL[bo + p * 512]);
        }
    };

    stage(0, 0);

    for (int kt = 0; kt < SEQ / 64; ++kt) {
        const int cur = kt & 1;
        const int k0  = kt * 64;

        __syncthreads();
        if (kt + 1 < SEQ / 64) stage(kt + 1, 1 - cur);

        // mask load + fold rescale: m' = m*log2e - 16*log2e
        float mreg[2][4][4];
        #pragma unroll
        for (int i = 0; i < 2; ++i)
            #pragma unroll
            for (int g = 0; g < 4; ++g) {
                const size_t mrow = (size_t)(q0 + w * 32 + i * 16 + qd * 4 + g) * SEQ + k0;
                #pragma unroll
                for (int j = 0; j < 4; ++j)
                    mreg[i][g][j] = fmaf(mask[mrow + j * 16 + r], LOG2E, C_MOFF);
            }

        const int co = cur * 4096;
        f32x4 S[2][4];
        #pragma unroll
        for (int i = 0; i < 2; ++i)
            #pragma unroll
            for (int j = 0; j < 4; ++j) S[i][j] = (f32x4){0.f, 0.f, 0.f, 0.f};
        #pragma unroll
        for (int ks = 0; ks < 2; ++ks) {
            bf16x8 kfh[4], kfl[4];
            #pragma unroll
            for (int j = 0; j < 4; ++j) {
                const int row = j * 16 + r;
                const int off = co + row * 64 + (((ks * 4 + qd) ^ (row & 7)) * 8);
                kfh[j] = __builtin_bit_cast(bf16x8, *(const s16x8*)&KhL[off]);
                kfl[j] = __builtin_bit_cast(bf16x8, *(const s16x8*)&KlL[off]);
            }
            #pragma unroll
            for (int i = 0; i < 2; ++i)
                #pragma unroll
                for (int j = 0; j < 4; ++j) {
                    S[i][j] = __builtin_amdgcn_mfma_f32_16x16x32_bf16(qh[i][ks], kfh[j], S[i][j], 0, 0, 0);
                    S[i][j] = __builtin_amdgcn_mfma_f32_16x16x32_bf16(qh[i][ks], kfl[j], S[i][j], 0, 0, 0);
                    S[i][j] = __builtin_amdgcn_mfma_f32_16x16x32_bf16(ql[i][ks], kfh[j], S[i][j], 0, 0, 0);
                }
        }

        // p = exp2(s * 0.125*log2e + m')
        #pragma unroll
        for (int i = 0; i < 2; ++i)
            #pragma unroll
            for (int j = 0; j < 4; ++j)
                #pragma unroll
                for (int g = 0; g < 4; ++g)
                    S[i][j][g] = exp2f(fmaf(S[i][j][g], C_SCALE, mreg[i][g][j]));

        #pragma unroll
        for (int i = 0; i < 2; ++i)
            #pragma unroll
            for (int j = 0; j < 4; ++j)
                #pragma unroll
                for (int g = 0; g < 4; ++g) {
                    const int prow = w * 32 + i * 16 + qd * 4 + g;
                    const int gr   = (j * 2 + (r >> 3)) ^ ((prow >> 1) & 7);
                    PhL[prow * 64 + gr * 8 + (r & 7)] = f2bf(S[i][j][g]);
                }

        #pragma unroll
        for (int ks = 0; ks < 2; ++ks) {
            bf16x8 pfh[2], vfh[4];
            #pragma unroll
            for (int i = 0; i < 2; ++i) {
                const int row = w * 32 + i * 16 + r;
                pfh[i] = __builtin_bit_cast(bf16x8,
                    *(const s16x8*)&PhL[row * 64 + (((ks * 4 + qd) ^ ((row >> 1) & 7)) * 8)]);
            }
            #pragma unroll
            for (int j = 0; j < 4; ++j) {
                const int row = j * 16 + r;
                vfh[j] = __builtin_bit_cast(bf16x8,
                    *(const s16x8*)&VhL[co + row * 64 + (((ks * 4 + qd) ^ (row & 7)) * 8)]);
            }
            #pragma unroll
            for (int i = 0; i < 2; ++i) {
                Lac[i] = __builtin_amdgcn_mfma_f32_16x16x32_bf16(pfh[i], ones, Lac[i], 0, 0, 0);
                #pragma unroll
                for (int j = 0; j < 4; ++j)
                    O[i][j] = __builtin_amdgcn_mfma_f32_16x16x32_bf16(pfh[i], vfh[j], O[i][j], 0, 0, 0);
            }
        }
    }

    #pragma unroll
    for (int i = 0; i < 2; ++i)
        #pragma unroll
        for (int g = 0; g < 4; ++g) {
            const float inv = 1.0f / Lac[i][g];
            const size_t row = (size_t)(b * SEQ + q0 + w * 32 + i * 16 + qd * 4 + g);
            #pragma unroll
            for (int j = 0; j < 4; ++j)
                atth[row * 1024 + h * 64 + j * 16 + r] = f2bf(O[i][j][g] * inv);
        }
}

// ---------------------------------------------------------------------------
extern "C" void kernel_launch(void* const* d_in, const int* in_sizes, int n_in,
                              void* d_out, int out_size, void* d_ws, size_t ws_size,
                              hipStream_t stream)
{
    const float* seq  = (const float*)d_in[0];
    const float* mask = (const float*)d_in[1];
    const float* Wqkv = (const float*)d_in[2];
    const float* W1   = (const float*)d_in[3];
    const float* b1   = (const float*)d_in[4];
    const float* W2   = (const float*)d_in[5];
    const float* b2   = (const float*)d_in[6];
    float* out = (float*)d_out;

    // ws (64 MiB): Xh[0,16) Xl[16,32) Vnat[32,40) Wt1[40,48) WtQ[48,60)
    //   after QKV: Vth[48,56) Wt2[56,64);  after attn: hidh[0,16)
    // d_out (16 MiB): seqh[0,8) -> atth[0,8) -> out[0,16)
    const size_t MiB = 1048576;
    char* B = (char*)d_ws;
    short* Xh   = (short*)(B + 0);
    short* Xl   = (short*)(B + 16 * MiB);
    short* Vnat = (short*)(B + 32 * MiB);
    short* Wt1h = (short*)(B + 40 * MiB);
    short* Wt1l = (short*)(B + 44 * MiB);
    short* WtQh = (short*)(B + 48 * MiB);
    short* WtQl = (short*)(B + 54 * MiB);
    short* Vth  = (short*)(B + 48 * MiB);
    short* Wt2h = (short*)(B + 56 * MiB);
    short* Wt2l = (short*)(B + 60 * MiB);
    short* hidh = (short*)(B + 0);

    short* seqh = (short*)d_out;
    short* atth = (short*)d_out;

    // P0: seq hi-split + Wqkv/W1 transpose-splits
    prep_kernel<<<6144, 256, 0, stream>>>(seq, seqh, Wqkv, WtQh, WtQl, W1, Wt1h, Wt1l);

    // P1: QKV (2-term) — Q|K split -> Xh/Xl, V natural bf16 -> Vnat
    gemm2<0, 1, 1, 128><<<dim3(3072 / 128, MTOT / 128), 256, 0, stream>>>(
        seqh, WtQh, WtQl, nullptr,
        nullptr, Xh, Xl, Vnat, MTOT, 3072, 1024, 2048);

    // P2: V transpose + W2 split
    util_kernel<<<6144, 256, 0, stream>>>(Vnat, Vth, W2, Wt2h, Wt2l);

    // P3: flash attention -> atth (hi only) in d_out
    attn_mfma3<<<dim3(BSZ * NHEAD, SEQ / 128), 256, 0, stream>>>(Xh, Xl, Vth, mask, atth);

    // P4: FFN1 + SiLU (2-term) -> hidh
    gemm2<1, 2, 0, 128><<<dim3(2048 / 128, MTOT / 128), 256, 0, stream>>>(
        atth, Wt1h, Wt1l, b1,
        nullptr, hidh, nullptr, nullptr, MTOT, 2048, 1024, 2048);

    // P5: FFN2 + bias (2-term) -> out
    gemm2<0, 0, 0, 64><<<dim3(1024 / 64, MTOT / 128), 256, 0, stream>>>(
        hidh, Wt2h, Wt2l, b2,
        out, nullptr, nullptr, nullptr, MTOT, 1024, 2048, 1024);
}